// Round 18
// baseline (1492.446 us; speedup 1.0000x reference)
//
#include <hip/hip_runtime.h>
#include <hip/hip_bf16.h>

#define N_PTS  65536
#define DMODEL 256
#define MSAMP  1024

#define NW    64   // FPS waves = single-wave workgroups (all co-resident)
#define FPT   16   // points per lane: 65536 / (64 * 64)
#define FPP   8    // point PAIRS per lane (f32x2 packed math)
#define SLW   16   // u64s per slot line: 128B stride, one wave per line
#define NCAND 8    // candidates published per wave (+1 bound slot) — R10 proven

typedef short bf16x8_t __attribute__((ext_vector_type(8)));
typedef float f32x4_t  __attribute__((ext_vector_type(4)));
typedef float f32x2_t  __attribute__((ext_vector_type(2)));

__device__ __forceinline__ short f2bs(float f) {
    __hip_bfloat16 h = __float2bfloat16(f);   // RNE
    return *reinterpret_cast<short*>(&h);
}

__device__ __forceinline__ bf16x8_t cvt8(const float* p) {
    f32x4_t a = *(const f32x4_t*)(p);
    f32x4_t b = *(const f32x4_t*)(p + 4);
    bf16x8_t r;
#pragma unroll
    for (int i = 0; i < 4; i++) { r[i] = f2bs(a[i]); r[i + 4] = f2bs(b[i]); }
    return r;
}

// u64 max via f64 fmax (packs are positive f64 bit patterns; proven R5-R17)
__device__ __forceinline__ unsigned long long dmax64(unsigned long long a,
                                                     unsigned long long b) {
    double r = fmax(__longlong_as_double((long long)a),
                    __longlong_as_double((long long)b));
    return (unsigned long long)__double_as_longlong(r);
}

// ---- full-wave max via DPP (VALU pipe) — R16 proven ----------------------
__device__ __forceinline__ unsigned wave_umax_dpp(unsigned v) {
    unsigned t;
    t = __builtin_amdgcn_update_dpp(0, (int)v, 0x111, 0xF, 0xF, false); v = v > (unsigned)t ? v : (unsigned)t;
    t = __builtin_amdgcn_update_dpp(0, (int)v, 0x112, 0xF, 0xF, false); v = v > (unsigned)t ? v : (unsigned)t;
    t = __builtin_amdgcn_update_dpp(0, (int)v, 0x114, 0xF, 0xF, false); v = v > (unsigned)t ? v : (unsigned)t;
    t = __builtin_amdgcn_update_dpp(0, (int)v, 0x118, 0xF, 0xF, false); v = v > (unsigned)t ? v : (unsigned)t;
    t = __builtin_amdgcn_update_dpp(0, (int)v, 0x142, 0xF, 0xF, false); v = v > (unsigned)t ? v : (unsigned)t;
    t = __builtin_amdgcn_update_dpp(0, (int)v, 0x143, 0xF, 0xF, false); v = v > (unsigned)t ? v : (unsigned)t;
    return (unsigned)__builtin_amdgcn_readlane((int)v, 63);
}
// R18: wave-max of pack (value<<32|inv_idx). Fast path: one DPP reduce on
// the value; if a UNIQUE lane holds it (ballot popcount==1, the ~always
// case for random f32 distances), fetch its low word via readlane. Ties
// (>=2 lanes) fall back to the full second reduce — result is bitwise
// identical to the two-reduce version in all cases. Branch is wave-uniform.
__device__ __forceinline__ unsigned long long wave_maxpack(unsigned long long p) {
    unsigned hv = (unsigned)(p >> 32);
    unsigned lv = (unsigned)p;
    unsigned gv = wave_umax_dpp(hv);
    unsigned long long m = __ballot(hv == gv);
    unsigned gl;
    if (__popcll(m) == 1) {
        gl = (unsigned)__builtin_amdgcn_readlane((int)lv, (int)(__ffsll(m) - 1));
    } else {
        gl = wave_umax_dpp((hv == gv) ? lv : 0u);
    }
    return (((unsigned long long)gv) << 32) | gl;
}

// ---------------------------------------------------------------------------
// Batched-candidate FPS, NCAND=8, DPP reduces, packed f32x2 distance math
// (R17, 642us). R18 change: wave_maxpack fast path (above). Protocol,
// exactness argument, and liveness class unchanged.
// ---------------------------------------------------------------------------
#pragma clang fp contract(off)
__global__ __launch_bounds__(64) void fps_kernel(
    const float*        __restrict__ xyz,      // (N,3) f32
    unsigned long long* __restrict__ slots,    // [2][NW][SLW] u64, zeroed per call
    int*                __restrict__ idx)      // (MSAMP) out
{
    const int l = threadIdx.x;       // 0..63
    const int g = blockIdx.x;        // 0..63
    const int base = g * (FPT * 64) + l;

    f32x2_t px2[FPP], py2[FPP], pz2[FPP], dd2[FPP];
    unsigned long long ivi[FPT];
    const float c0x = xyz[0], c0y = xyz[1], c0z = xyz[2];   // winner 0 = point 0
    {
        f32x2_t w0x = {c0x, c0x}, w0y = {c0y, c0y}, w0z = {c0z, c0z};
#pragma unroll
        for (int i = 0; i < FPP; i++) {
            int p0 = base + (2 * i) * 64;
            int p1 = base + (2 * i + 1) * 64;
            px2[i].x = xyz[3 * p0 + 0]; px2[i].y = xyz[3 * p1 + 0];
            py2[i].x = xyz[3 * p0 + 1]; py2[i].y = xyz[3 * p1 + 1];
            pz2[i].x = xyz[3 * p0 + 2]; pz2[i].y = xyz[3 * p1 + 2];
            ivi[2 * i]     = (unsigned long long)(0xFFFFu - (unsigned)p0);
            ivi[2 * i + 1] = (unsigned long long)(0xFFFFu - (unsigned)p1);
            f32x2_t dx = px2[i] - w0x, dy = py2[i] - w0y, dz = pz2[i] - w0z;
            f32x2_t d  = (dx * dx + dy * dy) + dz * dz;   // contract off: RN each op
            dd2[i].x = fminf(1e10f, d.x);
            dd2[i].y = fminf(1e10f, d.y);
        }
    }
    if (g == 0 && l == 0) idx[0] = 0;

    int total = 0, r = 0;
    while (total < MSAMP - 1) {
        ++r;
        // ---- 1) extract top-(NCAND+1) packs ------------------------------
        unsigned long long pk[FPT];
#pragma unroll
        for (int i = 0; i < FPP; i++) {
            pk[2 * i]     = (((unsigned long long)__float_as_uint(dd2[i].x)) << 32) | ivi[2 * i];
            pk[2 * i + 1] = (((unsigned long long)__float_as_uint(dd2[i].y)) << 32) | ivi[2 * i + 1];
        }

        unsigned long long top[NCAND + 1];
        unsigned long long prev = ~0ull;            // matches no pack
#pragma unroll
        for (int t = 0; t < NCAND + 1; t++) {
            unsigned long long lm = 0;
#pragma unroll
            for (int i = 0; i < FPT; i++) {
                pk[i] = (pk[i] == prev) ? 0ull : pk[i];
                lm = dmax64(lm, pk[i]);
            }
            unsigned long long gt = wave_maxpack(lm);
            top[t] = gt;
            prev = gt;
        }

        // ---- 2) publish (lanes 0..NCAND) + poll --------------------------
        const int ph = r & 1;
        const unsigned rt = (unsigned)(r & 0xFFFF);
        unsigned long long sv = top[0];
#pragma unroll
        for (int t = 1; t <= NCAND; t++) sv = (l == t) ? top[t] : sv;
        sv |= ((unsigned long long)rt) << 16;       // bits 16-31 free in packs
        if (l <= NCAND)
            __hip_atomic_store(slots + ((size_t)(ph * NW + g) * SLW + l), sv,
                               __ATOMIC_RELAXED, __HIP_MEMORY_SCOPE_AGENT);

        const unsigned long long* Q = slots + (size_t)ph * NW * SLW + (size_t)l * SLW;
        unsigned long long u[NCAND + 1];
        for (;;) {
            bool ok = true;
#pragma unroll
            for (int t = 0; t <= NCAND; t++) {
                u[t] = __hip_atomic_load(Q + t, __ATOMIC_RELAXED,
                                         __HIP_MEMORY_SCOPE_AGENT);
                ok &= (((unsigned)(u[t] >> 16) & 0xFFFFu) == rt);
            }
            if (__all(ok)) break;
            __builtin_amdgcn_s_sleep(2);
        }

        // ---- parse: lane l holds wave l's 8 candidates (as 4 pairs) ------
        f32x2_t cv2[NCAND / 2], cx2[NCAND / 2], cy2[NCAND / 2], cz2[NCAND / 2];
        unsigned ici[NCAND];
#pragma unroll
        for (int c = 0; c < NCAND / 2; c++) {
            unsigned long long u0 = u[2 * c], u1 = u[2 * c + 1];
            cv2[c].x = __uint_as_float((unsigned)(u0 >> 32));
            cv2[c].y = __uint_as_float((unsigned)(u1 >> 32));
            ici[2 * c]     = (unsigned)(u0 & 0xFFFFu);
            ici[2 * c + 1] = (unsigned)(u1 & 0xFFFFu);
            int p0 = 0xFFFF - (int)ici[2 * c];
            int p1 = 0xFFFF - (int)ici[2 * c + 1];
            cx2[c].x = xyz[3 * p0 + 0]; cx2[c].y = xyz[3 * p1 + 0];
            cy2[c].x = xyz[3 * p0 + 1]; cy2[c].y = xyz[3 * p1 + 1];
            cz2[c].x = xyz[3 * p0 + 2]; cz2[c].y = xyz[3 * p1 + 2];
        }
        float mB = __uint_as_float(wave_umax_dpp((unsigned)(u[NCAND] >> 32)));

        // ---- 3) emission loop (identical on every wave) ------------------
        int kk = 0;
        while (total < MSAMP - 1) {
            unsigned long long lb = 0;
#pragma unroll
            for (int c = 0; c < NCAND / 2; c++) {
                lb = dmax64(lb, (((unsigned long long)__float_as_uint(cv2[c].x)) << 32) | ici[2 * c]);
                lb = dmax64(lb, (((unsigned long long)__float_as_uint(cv2[c].y)) << 32) | ici[2 * c + 1]);
            }
            unsigned long long gb = wave_maxpack(lb);
            float gv = __uint_as_float((unsigned)(gb >> 32));
            if (kk > 0 && !(gv > mB)) break;     // strict >: exact vs unpublished

            int widx = 0xFFFF - (int)(gb & 0xFFFFu);
            if (g == 0 && l == 0) idx[total + 1] = widx;

            // winner coords from the owning lane (packs globally unique)
            float sx = cx2[0].x, sy = cy2[0].x, sz = cz2[0].x;
#pragma unroll
            for (int c = 0; c < NCAND / 2; c++) {
                bool h0 = ((((unsigned long long)__float_as_uint(cv2[c].x)) << 32) | ici[2 * c]) == gb;
                bool h1 = ((((unsigned long long)__float_as_uint(cv2[c].y)) << 32) | ici[2 * c + 1]) == gb;
                sx = h0 ? cx2[c].x : sx; sx = h1 ? cx2[c].y : sx;
                sy = h0 ? cy2[c].x : sy; sy = h1 ? cy2[c].y : sy;
                sz = h0 ? cz2[c].x : sz; sz = h1 ? cz2[c].y : sz;
            }
            unsigned long long mo = __ballot(lb == gb);
            int ol = __ffsll((unsigned long long)mo) - 1;
            float wx = __shfl(sx, ol, 64);
            float wy = __shfl(sy, ol, 64);
            float wz = __shfl(sz, ol, 64);

            f32x2_t wx2 = {wx, wx}, wy2 = {wy, wy}, wz2 = {wz, wz};
            // exact min-sequence updates: candidates AND local points (packed)
#pragma unroll
            for (int c = 0; c < NCAND / 2; c++) {
                f32x2_t dx = cx2[c] - wx2, dy = cy2[c] - wy2, dz = cz2[c] - wz2;
                f32x2_t d  = (dx * dx + dy * dy) + dz * dz;
                cv2[c].x = fminf(cv2[c].x, d.x);
                cv2[c].y = fminf(cv2[c].y, d.y);
            }
#pragma unroll
            for (int i = 0; i < FPP; i++) {
                f32x2_t dx = px2[i] - wx2, dy = py2[i] - wy2, dz = pz2[i] - wz2;
                f32x2_t d  = (dx * dx + dy * dy) + dz * dz;
                dd2[i].x = fminf(dd2[i].x, d.x);
                dd2[i].y = fminf(dd2[i].y, d.y);
            }

            total++; kk++;
        }
    }
}
#pragma clang fp contract(on)

// ---------------------------------------------------------------------------
// Gather + K/V projection in f32; outputs bf16. k pre-scaled by 1/16 (exact),
// row-major (j,k); v stored transposed (d,j).   [R10 verbatim, proven]
// ---------------------------------------------------------------------------
__global__ __launch_bounds__(256) void kv_kernel(
    const float* __restrict__ feat,
    const float* __restrict__ Wk, const float* __restrict__ bk,
    const float* __restrict__ Wv, const float* __restrict__ bv,
    const int* __restrict__ idx,
    unsigned short* __restrict__ k_s,   // (MSAMP, DMODEL) bf16, * 1/16
    unsigned short* __restrict__ vT)    // (DMODEL, MSAMP) bf16
{
    __shared__ float fl[4][DMODEL];
    const int t  = threadIdx.x;
    const int j0 = blockIdx.x * 4;
    {
        int jj = t >> 6;
        int e  = (t & 63) * 4;
        int src = idx[j0 + jj];
        f32x4_t v = *(const f32x4_t*)(feat + (size_t)src * DMODEL + e);
        fl[jj][e + 0] = v[0];
        fl[jj][e + 1] = v[1];
        fl[jj][e + 2] = v[2];
        fl[jj][e + 3] = v[3];
    }
    __syncthreads();

    float ak[4] = {0.f, 0.f, 0.f, 0.f};
    float av[4] = {0.f, 0.f, 0.f, 0.f};
    const float* wkr = Wk + (size_t)t * DMODEL;
    const float* wvr = Wv + (size_t)t * DMODEL;
#pragma unroll 4
    for (int in = 0; in < DMODEL; in += 4) {
        f32x4_t ku = *(const f32x4_t*)(wkr + in);
        f32x4_t vu = *(const f32x4_t*)(wvr + in);
#pragma unroll
        for (int jj = 0; jj < 4; jj++) {
            ak[jj] = fmaf(fl[jj][in + 0], ku[0], ak[jj]);
            ak[jj] = fmaf(fl[jj][in + 1], ku[1], ak[jj]);
            ak[jj] = fmaf(fl[jj][in + 2], ku[2], ak[jj]);
            ak[jj] = fmaf(fl[jj][in + 3], ku[3], ak[jj]);
            av[jj] = fmaf(fl[jj][in + 0], vu[0], av[jj]);
            av[jj] = fmaf(fl[jj][in + 1], vu[1], av[jj]);
            av[jj] = fmaf(fl[jj][in + 2], vu[2], av[jj]);
            av[jj] = fmaf(fl[jj][in + 3], vu[3], av[jj]);
        }
    }
    float bkv = bk[t];
    float bvv = bv[t];
#pragma unroll
    for (int jj = 0; jj < 4; jj++) {
        k_s[(unsigned)(j0 + jj) * DMODEL + t] = (unsigned short)f2bs((ak[jj] + bkv) * 0.0625f);
        vT[(unsigned)t * MSAMP + (j0 + jj)]   = (unsigned short)f2bs(av[jj] + bvv);
    }
}

// ---------------------------------------------------------------------------
// Fused q -> w -> res -> concat. 128-row tile, 4 waves (2 row x 2 col), MFMA
// 16x16x32 bf16, double-buffered wlds.   [R14 verbatim, proven best tail]
// R18: launched 4x (idempotent) as a timing diagnostic — main's duration has
// never been visible in the top-5; main = (total' - fps' - tail_known)/3.
// ---------------------------------------------------------------------------
#define QS  264
#define WSR 136
#define RS  258
#define WBUF (128 * WSR)                       // u16 elems per wlds buffer
#define MAIN_LDS (128 * QS * 2 + 2 * WBUF * 2) // 137216 B

__global__ __launch_bounds__(256, 1) void main_kernel(
    const float* __restrict__ feat,
    const float* __restrict__ Wq, const float* __restrict__ bq,
    const unsigned short* __restrict__ k_s,
    const unsigned short* __restrict__ vT,
    float* __restrict__ out)
{
    extern __shared__ char smem[];
    unsigned short* qlds = (unsigned short*)smem;
    unsigned short* wlds = (unsigned short*)(smem + 128 * QS * 2);

    const int tid  = threadIdx.x;
    const int ln   = tid & 63;
    const int wid  = tid >> 6;
    const int wr   = wid & 1;
    const int wc   = wid >> 1;
    const int r0   = blockIdx.x * 128;
    const int lrow = ln & 15;
    const int lk   = (ln >> 4) * 8;
    const int crow = (ln >> 4) * 4;

    const f32x4_t fzero = {0.f, 0.f, 0.f, 0.f};

    // ---- phase 1: q = feat @ Wq^T + bq -> bf16 in qlds ----
    f32x4_t qa[4][8];
#pragma unroll
    for (int m = 0; m < 4; m++)
#pragma unroll
        for (int n = 0; n < 8; n++) qa[m][n] = fzero;

#pragma unroll
    for (int kb = 0; kb < DMODEL; kb += 32) {
        bf16x8_t A[4], B[8];
#pragma unroll
        for (int m = 0; m < 4; m++)
            A[m] = cvt8(feat + (size_t)(r0 + wr * 64 + m * 16 + lrow) * DMODEL + kb + lk);
#pragma unroll
        for (int n = 0; n < 8; n++)
            B[n] = cvt8(Wq + (size_t)(wc * 128 + n * 16 + lrow) * DMODEL + kb + lk);
#pragma unroll
        for (int m = 0; m < 4; m++)
#pragma unroll
            for (int n = 0; n < 8; n++)
                qa[m][n] = __builtin_amdgcn_mfma_f32_16x16x32_bf16(
                    A[m], B[n], qa[m][n], 0, 0, 0);
    }
#pragma unroll
    for (int n = 0; n < 8; n++) {
        float bqv = bq[wc * 128 + n * 16 + lrow];
#pragma unroll
        for (int m = 0; m < 4; m++)
#pragma unroll
            for (int r = 0; r < 4; r++)
                qlds[(wr * 64 + m * 16 + crow + r) * QS + wc * 128 + n * 16 + lrow] =
                    (unsigned short)f2bs(qa[m][n][r] + bqv);
    }
    __syncthreads();

    // ---- phase 2: dbuf flash loop ----
    f32x4_t racc[4][8];
#pragma unroll
    for (int m = 0; m < 4; m++)
#pragma unroll
        for (int n = 0; n < 8; n++) racc[m][n] = fzero;

    // prologue: w(0) -> wlds buf 0
    {
        f32x4_t wa[4][4];
#pragma unroll
        for (int m = 0; m < 4; m++)
#pragma unroll
            for (int n = 0; n < 4; n++) wa[m][n] = fzero;
#pragma unroll
        for (int kb = 0; kb < DMODEL; kb += 32) {
            bf16x8_t A[4], B[4];
#pragma unroll
            for (int m = 0; m < 4; m++)
                A[m] = *(const bf16x8_t*)(qlds + (wr * 64 + m * 16 + lrow) * QS + kb + lk);
#pragma unroll
            for (int n = 0; n < 4; n++)
                B[n] = *(const bf16x8_t*)(k_s +
                    (size_t)(wc * 64 + n * 16 + lrow) * DMODEL + kb + lk);
#pragma unroll
            for (int m = 0; m < 4; m++)
#pragma unroll
                for (int n = 0; n < 4; n++)
                    wa[m][n] = __builtin_amdgcn_mfma_f32_16x16x32_bf16(
                        A[m], B[n], wa[m][n], 0, 0, 0);
        }
#pragma unroll
        for (int m = 0; m < 4; m++)
#pragma unroll
            for (int n = 0; n < 4; n++)
#pragma unroll
                for (int r = 0; r < 4; r++)
                    wlds[(wr * 64 + m * 16 + crow + r) * WSR + wc * 64 + n * 16 + lrow] =
                        (unsigned short)f2bs(wa[m][n][r]);
    }
    __syncthreads();

    for (int jb = 0; jb < 8; jb++) {
        const int cur = jb & 1;
        unsigned short* wcur = wlds + cur * WBUF;
        unsigned short* wnxt = wlds + (cur ^ 1) * WBUF;

        // produce w(jb+1) -> wnxt (independent of res(jb); co-scheduled)
        if (jb < 7) {
            f32x4_t wa[4][4];
#pragma unroll
            for (int m = 0; m < 4; m++)
#pragma unroll
                for (int n = 0; n < 4; n++) wa[m][n] = fzero;
#pragma unroll
            for (int kb = 0; kb < DMODEL; kb += 32) {
                bf16x8_t A[4], B[4];
#pragma unroll
                for (int m = 0; m < 4; m++)
                    A[m] = *(const bf16x8_t*)(qlds + (wr * 64 + m * 16 + lrow) * QS + kb + lk);
#pragma unroll
                for (int n = 0; n < 4; n++)
                    B[n] = *(const bf16x8_t*)(k_s +
                        (size_t)((jb + 1) * 128 + wc * 64 + n * 16 + lrow) * DMODEL + kb + lk);
#pragma unroll
                for (int m = 0; m < 4; m++)
#pragma unroll
                    for (int n = 0; n < 4; n++)
                        wa[m][n] = __builtin_amdgcn_mfma_f32_16x16x32_bf16(
                            A[m], B[n], wa[m][n], 0, 0, 0);
            }
#pragma unroll
            for (int m = 0; m < 4; m++)
#pragma unroll
                for (int n = 0; n < 4; n++)
#pragma unroll
                    for (int r = 0; r < 4; r++)
                        wnxt[(wr * 64 + m * 16 + crow + r) * WSR + wc * 64 + n * 16 + lrow] =
                            (unsigned short)f2bs(wa[m][n][r]);
        }

        // consume wcur for res(jb)
#pragma unroll
        for (int kb2 = 0; kb2 < 128; kb2 += 32) {
            bf16x8_t A[4], B[8];
#pragma unroll
            for (int m = 0; m < 4; m++)
                A[m] = *(const bf16x8_t*)(wcur + (wr * 64 + m * 16 + lrow) * WSR + kb2 + lk);
#pragma unroll
            for (int n = 0; n < 8; n++)
                B[n] = *(const bf16x8_t*)(vT +
                    (size_t)(wc * 128 + n * 16 + lrow) * MSAMP + jb * 128 + kb2 + lk);
#pragma unroll
            for (int m = 0; m < 4; m++)
#pragma unroll
                for (int n = 0; n < 8; n++)
                    racc[m][n] = __builtin_amdgcn_mfma_f32_16x16x32_bf16(
                        A[m], B[n], racc[m][n], 0, 0, 0);
        }
        __syncthreads();
    }

    // ---- phase 3: epilogue, f32 res -> LDS, coalesced f32 [res|feat] store ----
    float* rlds = (float*)smem;   // qlds/wlds dead now (final barrier above)
#pragma unroll
    for (int m = 0; m < 4; m++)
#pragma unroll
        for (int n = 0; n < 8; n++)
#pragma unroll
            for (int r = 0; r < 4; r++)
                rlds[(wr * 64 + m * 16 + crow + r) * RS + wc * 128 + n * 16 + lrow] =
                    racc[m][n][r];
    __syncthreads();

#pragma unroll
    for (int base = 0; base < 128; base += 4) {
        int row = base + wid;
        f32x4_t a = *(const f32x4_t*)(rlds + row * RS + ln * 4);
        f32x4_t b = *(const f32x4_t*)(feat + (size_t)(r0 + row) * DMODEL + ln * 4);
        *(f32x4_t*)(out + (size_t)(r0 + row) * 512 + ln * 4)       = a;
        *(f32x4_t*)(out + (size_t)(r0 + row) * 512 + 256 + ln * 4) = b;
    }
}

// ---------------------------------------------------------------------------
extern "C" void kernel_launch(void* const* d_in, const int* in_sizes, int n_in,
                              void* d_out, int out_size, void* d_ws, size_t ws_size,
                              hipStream_t stream) {
    const float* p_xyz = (const float*)d_in[0];
    const float* feat  = (const float*)d_in[1];
    const float* Wq    = (const float*)d_in[2];
    const float* bq    = (const float*)d_in[3];
    const float* Wk    = (const float*)d_in[4];
    const float* bk    = (const float*)d_in[5];
    const float* Wv    = (const float*)d_in[6];
    const float* bv    = (const float*)d_in[7];
    float* out = (float*)d_out;

    char* ws = (char*)d_ws;
    unsigned long long* slots = (unsigned long long*)ws;                //  16 KB [2][NW][SLW]
    int*                idx   = (int*)(ws + 16384);                     //   4 KB
    unsigned short*     k_s   = (unsigned short*)(ws + 32768);          // 512 KB
    unsigned short*     vT    = (unsigned short*)(ws + 32768 + 524288); // 512 KB

    hipMemsetAsync(d_ws, 0, 16384, stream);   // invalidate slots every call

    hipLaunchKernelGGL(fps_kernel, dim3(NW), dim3(64), 0, stream,
                       p_xyz, slots, idx);
    hipLaunchKernelGGL(kv_kernel, dim3(MSAMP / 4), dim3(256), 0, stream,
                       feat, Wk, bk, Wv, bv, idx, k_s, vT);
    hipFuncSetAttribute((const void*)main_kernel,
                        hipFuncAttributeMaxDynamicSharedMemorySize, MAIN_LDS);
    // R18 diagnostic: 4x idempotent launches to measure main's duration from
    // the total (main never appears in the rocprof top-5).
    for (int rep = 0; rep < 4; rep++)
        hipLaunchKernelGGL(main_kernel, dim3(N_PTS / 128), dim3(256), MAIN_LDS, stream,
                           feat, Wq, bq, k_s, vT, out);
}

// Round 19
// 901.989 us; speedup vs baseline: 1.6546x; 1.6546x over previous
//
#include <hip/hip_runtime.h>
#include <hip/hip_bf16.h>

#define N_PTS  65536
#define DMODEL 256
#define MSAMP  1024

#define NW    64   // FPS waves = single-wave workgroups (all co-resident)
#define FPT   16   // points per lane: 65536 / (64 * 64)
#define FPP   8    // point PAIRS per lane (f32x2 packed math)
#define SLW   16   // u64s per slot line: 128B stride, one wave per line
#define NCAND 8    // candidates published per wave (+1 bound slot) — R10 proven

typedef short bf16x8_t __attribute__((ext_vector_type(8)));
typedef float f32x4_t  __attribute__((ext_vector_type(4)));
typedef float f32x2_t  __attribute__((ext_vector_type(2)));

__device__ __forceinline__ short f2bs(float f) {
    __hip_bfloat16 h = __float2bfloat16(f);   // RNE
    return *reinterpret_cast<short*>(&h);
}

__device__ __forceinline__ bf16x8_t cvt8(const float* p) {
    f32x4_t a = *(const f32x4_t*)(p);
    f32x4_t b = *(const f32x4_t*)(p + 4);
    bf16x8_t r;
#pragma unroll
    for (int i = 0; i < 4; i++) { r[i] = f2bs(a[i]); r[i + 4] = f2bs(b[i]); }
    return r;
}

// u64 max via f64 fmax (packs are positive f64 bit patterns; proven R5-R18)
__device__ __forceinline__ unsigned long long dmax64(unsigned long long a,
                                                     unsigned long long b) {
    double r = fmax(__longlong_as_double((long long)a),
                    __longlong_as_double((long long)b));
    return (unsigned long long)__double_as_longlong(r);
}

// ---- full-wave max via DPP (VALU pipe) — R16 proven ----------------------
__device__ __forceinline__ unsigned wave_umax_dpp(unsigned v) {
    unsigned t;
    t = __builtin_amdgcn_update_dpp(0, (int)v, 0x111, 0xF, 0xF, false); v = v > (unsigned)t ? v : (unsigned)t;
    t = __builtin_amdgcn_update_dpp(0, (int)v, 0x112, 0xF, 0xF, false); v = v > (unsigned)t ? v : (unsigned)t;
    t = __builtin_amdgcn_update_dpp(0, (int)v, 0x114, 0xF, 0xF, false); v = v > (unsigned)t ? v : (unsigned)t;
    t = __builtin_amdgcn_update_dpp(0, (int)v, 0x118, 0xF, 0xF, false); v = v > (unsigned)t ? v : (unsigned)t;
    t = __builtin_amdgcn_update_dpp(0, (int)v, 0x142, 0xF, 0xF, false); v = v > (unsigned)t ? v : (unsigned)t;
    t = __builtin_amdgcn_update_dpp(0, (int)v, 0x143, 0xF, 0xF, false); v = v > (unsigned)t ? v : (unsigned)t;
    return (unsigned)__builtin_amdgcn_readlane((int)v, 63);
}
// R18-proven wave-max of pack with unique-value fast path (bitwise exact).
__device__ __forceinline__ unsigned long long wave_maxpack(unsigned long long p) {
    unsigned hv = (unsigned)(p >> 32);
    unsigned lv = (unsigned)p;
    unsigned gv = wave_umax_dpp(hv);
    unsigned long long m = __ballot(hv == gv);
    unsigned gl;
    if (__popcll(m) == 1) {
        gl = (unsigned)__builtin_amdgcn_readlane((int)lv, (int)(__ffsll(m) - 1));
    } else {
        gl = wave_umax_dpp((hv == gv) ? lv : 0u);
    }
    return (((unsigned long long)gv) << 32) | gl;
}

// ---------------------------------------------------------------------------
// Batched-candidate FPS — R18 verbatim (638us, best measured).
// ---------------------------------------------------------------------------
#pragma clang fp contract(off)
__global__ __launch_bounds__(64) void fps_kernel(
    const float*        __restrict__ xyz,      // (N,3) f32
    unsigned long long* __restrict__ slots,    // [2][NW][SLW] u64, zeroed per call
    int*                __restrict__ idx)      // (MSAMP) out
{
    const int l = threadIdx.x;       // 0..63
    const int g = blockIdx.x;        // 0..63
    const int base = g * (FPT * 64) + l;

    f32x2_t px2[FPP], py2[FPP], pz2[FPP], dd2[FPP];
    unsigned long long ivi[FPT];
    const float c0x = xyz[0], c0y = xyz[1], c0z = xyz[2];   // winner 0 = point 0
    {
        f32x2_t w0x = {c0x, c0x}, w0y = {c0y, c0y}, w0z = {c0z, c0z};
#pragma unroll
        for (int i = 0; i < FPP; i++) {
            int p0 = base + (2 * i) * 64;
            int p1 = base + (2 * i + 1) * 64;
            px2[i].x = xyz[3 * p0 + 0]; px2[i].y = xyz[3 * p1 + 0];
            py2[i].x = xyz[3 * p0 + 1]; py2[i].y = xyz[3 * p1 + 1];
            pz2[i].x = xyz[3 * p0 + 2]; pz2[i].y = xyz[3 * p1 + 2];
            ivi[2 * i]     = (unsigned long long)(0xFFFFu - (unsigned)p0);
            ivi[2 * i + 1] = (unsigned long long)(0xFFFFu - (unsigned)p1);
            f32x2_t dx = px2[i] - w0x, dy = py2[i] - w0y, dz = pz2[i] - w0z;
            f32x2_t d  = (dx * dx + dy * dy) + dz * dz;   // contract off: RN each op
            dd2[i].x = fminf(1e10f, d.x);
            dd2[i].y = fminf(1e10f, d.y);
        }
    }
    if (g == 0 && l == 0) idx[0] = 0;

    int total = 0, r = 0;
    while (total < MSAMP - 1) {
        ++r;
        unsigned long long pk[FPT];
#pragma unroll
        for (int i = 0; i < FPP; i++) {
            pk[2 * i]     = (((unsigned long long)__float_as_uint(dd2[i].x)) << 32) | ivi[2 * i];
            pk[2 * i + 1] = (((unsigned long long)__float_as_uint(dd2[i].y)) << 32) | ivi[2 * i + 1];
        }

        unsigned long long top[NCAND + 1];
        unsigned long long prev = ~0ull;            // matches no pack
#pragma unroll
        for (int t = 0; t < NCAND + 1; t++) {
            unsigned long long lm = 0;
#pragma unroll
            for (int i = 0; i < FPT; i++) {
                pk[i] = (pk[i] == prev) ? 0ull : pk[i];
                lm = dmax64(lm, pk[i]);
            }
            unsigned long long gt = wave_maxpack(lm);
            top[t] = gt;
            prev = gt;
        }

        const int ph = r & 1;
        const unsigned rt = (unsigned)(r & 0xFFFF);
        unsigned long long sv = top[0];
#pragma unroll
        for (int t = 1; t <= NCAND; t++) sv = (l == t) ? top[t] : sv;
        sv |= ((unsigned long long)rt) << 16;       // bits 16-31 free in packs
        if (l <= NCAND)
            __hip_atomic_store(slots + ((size_t)(ph * NW + g) * SLW + l), sv,
                               __ATOMIC_RELAXED, __HIP_MEMORY_SCOPE_AGENT);

        const unsigned long long* Q = slots + (size_t)ph * NW * SLW + (size_t)l * SLW;
        unsigned long long u[NCAND + 1];
        for (;;) {
            bool ok = true;
#pragma unroll
            for (int t = 0; t <= NCAND; t++) {
                u[t] = __hip_atomic_load(Q + t, __ATOMIC_RELAXED,
                                         __HIP_MEMORY_SCOPE_AGENT);
                ok &= (((unsigned)(u[t] >> 16) & 0xFFFFu) == rt);
            }
            if (__all(ok)) break;
            __builtin_amdgcn_s_sleep(2);
        }

        f32x2_t cv2[NCAND / 2], cx2[NCAND / 2], cy2[NCAND / 2], cz2[NCAND / 2];
        unsigned ici[NCAND];
#pragma unroll
        for (int c = 0; c < NCAND / 2; c++) {
            unsigned long long u0 = u[2 * c], u1 = u[2 * c + 1];
            cv2[c].x = __uint_as_float((unsigned)(u0 >> 32));
            cv2[c].y = __uint_as_float((unsigned)(u1 >> 32));
            ici[2 * c]     = (unsigned)(u0 & 0xFFFFu);
            ici[2 * c + 1] = (unsigned)(u1 & 0xFFFFu);
            int p0 = 0xFFFF - (int)ici[2 * c];
            int p1 = 0xFFFF - (int)ici[2 * c + 1];
            cx2[c].x = xyz[3 * p0 + 0]; cx2[c].y = xyz[3 * p1 + 0];
            cy2[c].x = xyz[3 * p0 + 1]; cy2[c].y = xyz[3 * p1 + 1];
            cz2[c].x = xyz[3 * p0 + 2]; cz2[c].y = xyz[3 * p1 + 2];
        }
        float mB = __uint_as_float(wave_umax_dpp((unsigned)(u[NCAND] >> 32)));

        int kk = 0;
        while (total < MSAMP - 1) {
            unsigned long long lb = 0;
#pragma unroll
            for (int c = 0; c < NCAND / 2; c++) {
                lb = dmax64(lb, (((unsigned long long)__float_as_uint(cv2[c].x)) << 32) | ici[2 * c]);
                lb = dmax64(lb, (((unsigned long long)__float_as_uint(cv2[c].y)) << 32) | ici[2 * c + 1]);
            }
            unsigned long long gb = wave_maxpack(lb);
            float gv = __uint_as_float((unsigned)(gb >> 32));
            if (kk > 0 && !(gv > mB)) break;     // strict >: exact vs unpublished

            int widx = 0xFFFF - (int)(gb & 0xFFFFu);
            if (g == 0 && l == 0) idx[total + 1] = widx;

            float sx = cx2[0].x, sy = cy2[0].x, sz = cz2[0].x;
#pragma unroll
            for (int c = 0; c < NCAND / 2; c++) {
                bool h0 = ((((unsigned long long)__float_as_uint(cv2[c].x)) << 32) | ici[2 * c]) == gb;
                bool h1 = ((((unsigned long long)__float_as_uint(cv2[c].y)) << 32) | ici[2 * c + 1]) == gb;
                sx = h0 ? cx2[c].x : sx; sx = h1 ? cx2[c].y : sx;
                sy = h0 ? cy2[c].x : sy; sy = h1 ? cy2[c].y : sy;
                sz = h0 ? cz2[c].x : sz; sz = h1 ? cz2[c].y : sz;
            }
            unsigned long long mo = __ballot(lb == gb);
            int ol = __ffsll((unsigned long long)mo) - 1;
            float wx = __shfl(sx, ol, 64);
            float wy = __shfl(sy, ol, 64);
            float wz = __shfl(sz, ol, 64);

            f32x2_t wx2 = {wx, wx}, wy2 = {wy, wy}, wz2 = {wz, wz};
#pragma unroll
            for (int c = 0; c < NCAND / 2; c++) {
                f32x2_t dx = cx2[c] - wx2, dy = cy2[c] - wy2, dz = cz2[c] - wz2;
                f32x2_t d  = (dx * dx + dy * dy) + dz * dz;
                cv2[c].x = fminf(cv2[c].x, d.x);
                cv2[c].y = fminf(cv2[c].y, d.y);
            }
#pragma unroll
            for (int i = 0; i < FPP; i++) {
                f32x2_t dx = px2[i] - wx2, dy = py2[i] - wy2, dz = pz2[i] - wz2;
                f32x2_t d  = (dx * dx + dy * dy) + dz * dz;
                dd2[i].x = fminf(dd2[i].x, d.x);
                dd2[i].y = fminf(dd2[i].y, d.y);
            }

            total++; kk++;
        }
    }
}
#pragma clang fp contract(on)

// ---------------------------------------------------------------------------
// Gather + K/V projection in f32; outputs bf16.   [R10 verbatim, proven]
// ---------------------------------------------------------------------------
__global__ __launch_bounds__(256) void kv_kernel(
    const float* __restrict__ feat,
    const float* __restrict__ Wk, const float* __restrict__ bk,
    const float* __restrict__ Wv, const float* __restrict__ bv,
    const int* __restrict__ idx,
    unsigned short* __restrict__ k_s,   // (MSAMP, DMODEL) bf16, * 1/16
    unsigned short* __restrict__ vT)    // (DMODEL, MSAMP) bf16
{
    __shared__ float fl[4][DMODEL];
    const int t  = threadIdx.x;
    const int j0 = blockIdx.x * 4;
    {
        int jj = t >> 6;
        int e  = (t & 63) * 4;
        int src = idx[j0 + jj];
        f32x4_t v = *(const f32x4_t*)(feat + (size_t)src * DMODEL + e);
        fl[jj][e + 0] = v[0];
        fl[jj][e + 1] = v[1];
        fl[jj][e + 2] = v[2];
        fl[jj][e + 3] = v[3];
    }
    __syncthreads();

    float ak[4] = {0.f, 0.f, 0.f, 0.f};
    float av[4] = {0.f, 0.f, 0.f, 0.f};
    const float* wkr = Wk + (size_t)t * DMODEL;
    const float* wvr = Wv + (size_t)t * DMODEL;
#pragma unroll 4
    for (int in = 0; in < DMODEL; in += 4) {
        f32x4_t ku = *(const f32x4_t*)(wkr + in);
        f32x4_t vu = *(const f32x4_t*)(wvr + in);
#pragma unroll
        for (int jj = 0; jj < 4; jj++) {
            ak[jj] = fmaf(fl[jj][in + 0], ku[0], ak[jj]);
            ak[jj] = fmaf(fl[jj][in + 1], ku[1], ak[jj]);
            ak[jj] = fmaf(fl[jj][in + 2], ku[2], ak[jj]);
            ak[jj] = fmaf(fl[jj][in + 3], ku[3], ak[jj]);
            av[jj] = fmaf(fl[jj][in + 0], vu[0], av[jj]);
            av[jj] = fmaf(fl[jj][in + 1], vu[1], av[jj]);
            av[jj] = fmaf(fl[jj][in + 2], vu[2], av[jj]);
            av[jj] = fmaf(fl[jj][in + 3], vu[3], av[jj]);
        }
    }
    float bkv = bk[t];
    float bvv = bv[t];
#pragma unroll
    for (int jj = 0; jj < 4; jj++) {
        k_s[(unsigned)(j0 + jj) * DMODEL + t] = (unsigned short)f2bs((ak[jj] + bkv) * 0.0625f);
        vT[(unsigned)t * MSAMP + (j0 + jj)]   = (unsigned short)f2bs(av[jj] + bvv);
    }
}

#define QS  264
#define WSR 136
#define RS  258
#define WBUF (128 * WSR)                        // u16 elems per wlds buffer
#define PREP_LDS (128 * QS * 2)                 // 67584 B
#define MAIN2_LDS (2 * WBUF * 2)                // 69632 B -> 2 blocks/CU
#define MAIN_LDS (128 * QS * 2 + 2 * WBUF * 2)  // 137216 B (fallback main)

// ---------------------------------------------------------------------------
// R19 prep_q: q = feat @ Wq^T + bq -> bf16 qb (global). Same arithmetic as
// the old phase 1 (bitwise identical q values); LDS repack for coalesced
// stores; 67.6KB LDS -> 2 blocks/CU, runs latency-hidden standalone.
// ---------------------------------------------------------------------------
__global__ __launch_bounds__(256) void prep_q_kernel(
    const float* __restrict__ feat,
    const float* __restrict__ Wq, const float* __restrict__ bq,
    unsigned short* __restrict__ qb)   // (N, D) bf16
{
    extern __shared__ char smem[];
    unsigned short* qlds = (unsigned short*)smem;

    const int tid  = threadIdx.x;
    const int ln   = tid & 63;
    const int wid  = tid >> 6;
    const int wr   = wid & 1;
    const int wc   = wid >> 1;
    const int r0   = blockIdx.x * 128;
    const int lrow = ln & 15;
    const int lk   = (ln >> 4) * 8;
    const int crow = (ln >> 4) * 4;

    const f32x4_t fzero = {0.f, 0.f, 0.f, 0.f};
    f32x4_t qa[4][8];
#pragma unroll
    for (int m = 0; m < 4; m++)
#pragma unroll
        for (int n = 0; n < 8; n++) qa[m][n] = fzero;

#pragma unroll
    for (int kb = 0; kb < DMODEL; kb += 32) {
        bf16x8_t A[4], B[8];
#pragma unroll
        for (int m = 0; m < 4; m++)
            A[m] = cvt8(feat + (size_t)(r0 + wr * 64 + m * 16 + lrow) * DMODEL + kb + lk);
#pragma unroll
        for (int n = 0; n < 8; n++)
            B[n] = cvt8(Wq + (size_t)(wc * 128 + n * 16 + lrow) * DMODEL + kb + lk);
#pragma unroll
        for (int m = 0; m < 4; m++)
#pragma unroll
            for (int n = 0; n < 8; n++)
                qa[m][n] = __builtin_amdgcn_mfma_f32_16x16x32_bf16(
                    A[m], B[n], qa[m][n], 0, 0, 0);
    }
#pragma unroll
    for (int n = 0; n < 8; n++) {
        float bqv = bq[wc * 128 + n * 16 + lrow];
#pragma unroll
        for (int m = 0; m < 4; m++)
#pragma unroll
            for (int r = 0; r < 4; r++)
                qlds[(wr * 64 + m * 16 + crow + r) * QS + wc * 128 + n * 16 + lrow] =
                    (unsigned short)f2bs(qa[m][n][r] + bqv);
    }
    __syncthreads();

    // coalesced qlds -> qb
#pragma unroll
    for (int c = tid; c < 128 * 32; c += 256) {
        int row = c >> 5, col = (c & 31) * 8;
        *(bf16x8_t*)(qb + (size_t)(r0 + row) * DMODEL + col) =
            *(const bf16x8_t*)(qlds + row * QS + col);
    }
}

// ---------------------------------------------------------------------------
// R19 main2: w -> res -> concat only. A-fragments read directly from global
// qb (L2-resident, same access shape as k_s loads). LDS = dbuf wlds only
// (69.6KB) -> 2 blocks/CU = 2 waves/SIMD (2x latency hiding vs old main).
// Epilogue stages res per 64-row half in the wlds space. Arithmetic is
// op-for-op identical to the R14 main.
// ---------------------------------------------------------------------------
__global__ __launch_bounds__(256) void main2_kernel(
    const float* __restrict__ feat,
    const unsigned short* __restrict__ qb,
    const unsigned short* __restrict__ k_s,
    const unsigned short* __restrict__ vT,
    float* __restrict__ out)
{
    extern __shared__ char smem[];
    unsigned short* wlds = (unsigned short*)smem;

    const int tid  = threadIdx.x;
    const int ln   = tid & 63;
    const int wid  = tid >> 6;
    const int wr   = wid & 1;
    const int wc   = wid >> 1;
    const int r0   = blockIdx.x * 128;
    const int lrow = ln & 15;
    const int lk   = (ln >> 4) * 8;
    const int crow = (ln >> 4) * 4;

    const f32x4_t fzero = {0.f, 0.f, 0.f, 0.f};

    f32x4_t racc[4][8];
#pragma unroll
    for (int m = 0; m < 4; m++)
#pragma unroll
        for (int n = 0; n < 8; n++) racc[m][n] = fzero;

    // prologue: w(0) -> wlds buf 0
    {
        f32x4_t wa[4][4];
#pragma unroll
        for (int m = 0; m < 4; m++)
#pragma unroll
            for (int n = 0; n < 4; n++) wa[m][n] = fzero;
#pragma unroll
        for (int kb = 0; kb < DMODEL; kb += 32) {
            bf16x8_t A[4], B[4];
#pragma unroll
            for (int m = 0; m < 4; m++)
                A[m] = *(const bf16x8_t*)(qb +
                    (size_t)(r0 + wr * 64 + m * 16 + lrow) * DMODEL + kb + lk);
#pragma unroll
            for (int n = 0; n < 4; n++)
                B[n] = *(const bf16x8_t*)(k_s +
                    (size_t)(wc * 64 + n * 16 + lrow) * DMODEL + kb + lk);
#pragma unroll
            for (int m = 0; m < 4; m++)
#pragma unroll
                for (int n = 0; n < 4; n++)
                    wa[m][n] = __builtin_amdgcn_mfma_f32_16x16x32_bf16(
                        A[m], B[n], wa[m][n], 0, 0, 0);
        }
#pragma unroll
        for (int m = 0; m < 4; m++)
#pragma unroll
            for (int n = 0; n < 4; n++)
#pragma unroll
                for (int r = 0; r < 4; r++)
                    wlds[(wr * 64 + m * 16 + crow + r) * WSR + wc * 64 + n * 16 + lrow] =
                        (unsigned short)f2bs(wa[m][n][r]);
    }
    __syncthreads();

    for (int jb = 0; jb < 8; jb++) {
        const int cur = jb & 1;
        unsigned short* wcur = wlds + cur * WBUF;
        unsigned short* wnxt = wlds + (cur ^ 1) * WBUF;

        if (jb < 7) {
            f32x4_t wa[4][4];
#pragma unroll
            for (int m = 0; m < 4; m++)
#pragma unroll
                for (int n = 0; n < 4; n++) wa[m][n] = fzero;
#pragma unroll
            for (int kb = 0; kb < DMODEL; kb += 32) {
                bf16x8_t A[4], B[4];
#pragma unroll
                for (int m = 0; m < 4; m++)
                    A[m] = *(const bf16x8_t*)(qb +
                        (size_t)(r0 + wr * 64 + m * 16 + lrow) * DMODEL + kb + lk);
#pragma unroll
                for (int n = 0; n < 4; n++)
                    B[n] = *(const bf16x8_t*)(k_s +
                        (size_t)((jb + 1) * 128 + wc * 64 + n * 16 + lrow) * DMODEL + kb + lk);
#pragma unroll
                for (int m = 0; m < 4; m++)
#pragma unroll
                    for (int n = 0; n < 4; n++)
                        wa[m][n] = __builtin_amdgcn_mfma_f32_16x16x32_bf16(
                            A[m], B[n], wa[m][n], 0, 0, 0);
            }
#pragma unroll
            for (int m = 0; m < 4; m++)
#pragma unroll
                for (int n = 0; n < 4; n++)
#pragma unroll
                    for (int r = 0; r < 4; r++)
                        wnxt[(wr * 64 + m * 16 + crow + r) * WSR + wc * 64 + n * 16 + lrow] =
                            (unsigned short)f2bs(wa[m][n][r]);
        }

#pragma unroll
        for (int kb2 = 0; kb2 < 128; kb2 += 32) {
            bf16x8_t A[4], B[8];
#pragma unroll
            for (int m = 0; m < 4; m++)
                A[m] = *(const bf16x8_t*)(wcur + (wr * 64 + m * 16 + lrow) * WSR + kb2 + lk);
#pragma unroll
            for (int n = 0; n < 8; n++)
                B[n] = *(const bf16x8_t*)(vT +
                    (size_t)(wc * 128 + n * 16 + lrow) * MSAMP + jb * 128 + kb2 + lk);
#pragma unroll
            for (int m = 0; m < 4; m++)
#pragma unroll
                for (int n = 0; n < 8; n++)
                    racc[m][n] = __builtin_amdgcn_mfma_f32_16x16x32_bf16(
                        A[m], B[n], racc[m][n], 0, 0, 0);
        }
        __syncthreads();
    }

    // ---- epilogue: two 64-row halves staged in the wlds space ------------
    float* rlds = (float*)smem;   // 64*RS*4 = 66048 <= 69632
#pragma unroll
    for (int half = 0; half < 2; half++) {
        if (wr == half) {
#pragma unroll
            for (int m = 0; m < 4; m++)
#pragma unroll
                for (int n = 0; n < 8; n++)
#pragma unroll
                    for (int r = 0; r < 4; r++)
                        rlds[(m * 16 + crow + r) * RS + wc * 128 + n * 16 + lrow] =
                            racc[m][n][r];
        }
        __syncthreads();
#pragma unroll
        for (int base = 0; base < 64; base += 4) {
            int row = base + wid;
            f32x4_t a = *(const f32x4_t*)(rlds + row * RS + ln * 4);
            f32x4_t b = *(const f32x4_t*)(feat +
                (size_t)(r0 + half * 64 + row) * DMODEL + ln * 4);
            *(f32x4_t*)(out + (size_t)(r0 + half * 64 + row) * 512 + ln * 4)       = a;
            *(f32x4_t*)(out + (size_t)(r0 + half * 64 + row) * 512 + 256 + ln * 4) = b;
        }
        __syncthreads();
    }
}

// ---------------------------------------------------------------------------
// Fallback fused main (R14 verbatim) — used only if ws can't hold qb.
// ---------------------------------------------------------------------------
__global__ __launch_bounds__(256, 1) void main_kernel(
    const float* __restrict__ feat,
    const float* __restrict__ Wq, const float* __restrict__ bq,
    const unsigned short* __restrict__ k_s,
    const unsigned short* __restrict__ vT,
    float* __restrict__ out)
{
    extern __shared__ char smem[];
    unsigned short* qlds = (unsigned short*)smem;
    unsigned short* wlds = (unsigned short*)(smem + 128 * QS * 2);

    const int tid  = threadIdx.x;
    const int ln   = tid & 63;
    const int wid  = tid >> 6;
    const int wr   = wid & 1;
    const int wc   = wid >> 1;
    const int r0   = blockIdx.x * 128;
    const int lrow = ln & 15;
    const int lk   = (ln >> 4) * 8;
    const int crow = (ln >> 4) * 4;

    const f32x4_t fzero = {0.f, 0.f, 0.f, 0.f};

    f32x4_t qa[4][8];
#pragma unroll
    for (int m = 0; m < 4; m++)
#pragma unroll
        for (int n = 0; n < 8; n++) qa[m][n] = fzero;

#pragma unroll
    for (int kb = 0; kb < DMODEL; kb += 32) {
        bf16x8_t A[4], B[8];
#pragma unroll
        for (int m = 0; m < 4; m++)
            A[m] = cvt8(feat + (size_t)(r0 + wr * 64 + m * 16 + lrow) * DMODEL + kb + lk);
#pragma unroll
        for (int n = 0; n < 8; n++)
            B[n] = cvt8(Wq + (size_t)(wc * 128 + n * 16 + lrow) * DMODEL + kb + lk);
#pragma unroll
        for (int m = 0; m < 4; m++)
#pragma unroll
            for (int n = 0; n < 8; n++)
                qa[m][n] = __builtin_amdgcn_mfma_f32_16x16x32_bf16(
                    A[m], B[n], qa[m][n], 0, 0, 0);
    }
#pragma unroll
    for (int n = 0; n < 8; n++) {
        float bqv = bq[wc * 128 + n * 16 + lrow];
#pragma unroll
        for (int m = 0; m < 4; m++)
#pragma unroll
            for (int r = 0; r < 4; r++)
                qlds[(wr * 64 + m * 16 + crow + r) * QS + wc * 128 + n * 16 + lrow] =
                    (unsigned short)f2bs(qa[m][n][r] + bqv);
    }
    __syncthreads();

    f32x4_t racc[4][8];
#pragma unroll
    for (int m = 0; m < 4; m++)
#pragma unroll
        for (int n = 0; n < 8; n++) racc[m][n] = fzero;

    {
        f32x4_t wa[4][4];
#pragma unroll
        for (int m = 0; m < 4; m++)
#pragma unroll
            for (int n = 0; n < 4; n++) wa[m][n] = fzero;
#pragma unroll
        for (int kb = 0; kb < DMODEL; kb += 32) {
            bf16x8_t A[4], B[4];
#pragma unroll
            for (int m = 0; m < 4; m++)
                A[m] = *(const bf16x8_t*)(qlds + (wr * 64 + m * 16 + lrow) * QS + kb + lk);
#pragma unroll
            for (int n = 0; n < 4; n++)
                B[n] = *(const bf16x8_t*)(k_s +
                    (size_t)(wc * 64 + n * 16 + lrow) * DMODEL + kb + lk);
#pragma unroll
            for (int m = 0; m < 4; m++)
#pragma unroll
                for (int n = 0; n < 4; n++)
                    wa[m][n] = __builtin_amdgcn_mfma_f32_16x16x32_bf16(
                        A[m], B[n], wa[m][n], 0, 0, 0);
        }
#pragma unroll
        for (int m = 0; m < 4; m++)
#pragma unroll
            for (int n = 0; n < 4; n++)
#pragma unroll
                for (int r = 0; r < 4; r++)
                    wlds[(wr * 64 + m * 16 + crow + r) * WSR + wc * 64 + n * 16 + lrow] =
                        (unsigned short)f2bs(wa[m][n][r]);
    }
    __syncthreads();

    for (int jb = 0; jb < 8; jb++) {
        const int cur = jb & 1;
        unsigned short* wcur = wlds + cur * WBUF;
        unsigned short* wnxt = wlds + (cur ^ 1) * WBUF;

        if (jb < 7) {
            f32x4_t wa[4][4];
#pragma unroll
            for (int m = 0; m < 4; m++)
#pragma unroll
                for (int n = 0; n < 4; n++) wa[m][n] = fzero;
#pragma unroll
            for (int kb = 0; kb < DMODEL; kb += 32) {
                bf16x8_t A[4], B[4];
#pragma unroll
                for (int m = 0; m < 4; m++)
                    A[m] = *(const bf16x8_t*)(qlds + (wr * 64 + m * 16 + lrow) * QS + kb + lk);
#pragma unroll
                for (int n = 0; n < 4; n++)
                    B[n] = *(const bf16x8_t*)(k_s +
                        (size_t)((jb + 1) * 128 + wc * 64 + n * 16 + lrow) * DMODEL + kb + lk);
#pragma unroll
                for (int m = 0; m < 4; m++)
#pragma unroll
                    for (int n = 0; n < 4; n++)
                        wa[m][n] = __builtin_amdgcn_mfma_f32_16x16x32_bf16(
                            A[m], B[n], wa[m][n], 0, 0, 0);
            }
#pragma unroll
            for (int m = 0; m < 4; m++)
#pragma unroll
                for (int n = 0; n < 4; n++)
#pragma unroll
                    for (int r = 0; r < 4; r++)
                        wnxt[(wr * 64 + m * 16 + crow + r) * WSR + wc * 64 + n * 16 + lrow] =
                            (unsigned short)f2bs(wa[m][n][r]);
        }

#pragma unroll
        for (int kb2 = 0; kb2 < 128; kb2 += 32) {
            bf16x8_t A[4], B[8];
#pragma unroll
            for (int m = 0; m < 4; m++)
                A[m] = *(const bf16x8_t*)(wcur + (wr * 64 + m * 16 + lrow) * WSR + kb2 + lk);
#pragma unroll
            for (int n = 0; n < 8; n++)
                B[n] = *(const bf16x8_t*)(vT +
                    (size_t)(wc * 128 + n * 16 + lrow) * MSAMP + jb * 128 + kb2 + lk);
#pragma unroll
            for (int m = 0; m < 4; m++)
#pragma unroll
                for (int n = 0; n < 8; n++)
                    racc[m][n] = __builtin_amdgcn_mfma_f32_16x16x32_bf16(
                        A[m], B[n], racc[m][n], 0, 0, 0);
        }
        __syncthreads();
    }

    float* rlds = (float*)smem;
#pragma unroll
    for (int m = 0; m < 4; m++)
#pragma unroll
        for (int n = 0; n < 8; n++)
#pragma unroll
            for (int r = 0; r < 4; r++)
                rlds[(wr * 64 + m * 16 + crow + r) * RS + wc * 128 + n * 16 + lrow] =
                    racc[m][n][r];
    __syncthreads();

#pragma unroll
    for (int base = 0; base < 128; base += 4) {
        int row = base + wid;
        f32x4_t a = *(const f32x4_t*)(rlds + row * RS + ln * 4);
        f32x4_t b = *(const f32x4_t*)(feat + (size_t)(r0 + row) * DMODEL + ln * 4);
        *(f32x4_t*)(out + (size_t)(r0 + row) * 512 + ln * 4)       = a;
        *(f32x4_t*)(out + (size_t)(r0 + row) * 512 + 256 + ln * 4) = b;
    }
}

// ---------------------------------------------------------------------------
extern "C" void kernel_launch(void* const* d_in, const int* in_sizes, int n_in,
                              void* d_out, int out_size, void* d_ws, size_t ws_size,
                              hipStream_t stream) {
    const float* p_xyz = (const float*)d_in[0];
    const float* feat  = (const float*)d_in[1];
    const float* Wq    = (const float*)d_in[2];
    const float* bq    = (const float*)d_in[3];
    const float* Wk    = (const float*)d_in[4];
    const float* bk    = (const float*)d_in[5];
    const float* Wv    = (const float*)d_in[6];
    const float* bv    = (const float*)d_in[7];
    float* out = (float*)d_out;

    char* ws = (char*)d_ws;
    unsigned long long* slots = (unsigned long long*)ws;                //  16 KB [2][NW][SLW]
    int*                idx   = (int*)(ws + 16384);                     //   4 KB
    unsigned short*     k_s   = (unsigned short*)(ws + 32768);          // 512 KB
    unsigned short*     vT    = (unsigned short*)(ws + 32768 + 524288); // 512 KB
    size_t qb_off = 32768 + 2 * 524288;
    size_t req    = qb_off + (size_t)N_PTS * DMODEL * 2;                // +33.5 MB
    int split = (ws_size >= req) ? 1 : 0;
    unsigned short* qb = (unsigned short*)(ws + qb_off);

    hipMemsetAsync(d_ws, 0, 16384, stream);   // invalidate slots every call

    hipLaunchKernelGGL(fps_kernel, dim3(NW), dim3(64), 0, stream,
                       p_xyz, slots, idx);
    hipLaunchKernelGGL(kv_kernel, dim3(MSAMP / 4), dim3(256), 0, stream,
                       feat, Wk, bk, Wv, bv, idx, k_s, vT);
    if (split) {
        hipFuncSetAttribute((const void*)prep_q_kernel,
                            hipFuncAttributeMaxDynamicSharedMemorySize, PREP_LDS);
        hipLaunchKernelGGL(prep_q_kernel, dim3(N_PTS / 128), dim3(256), PREP_LDS,
                           stream, feat, Wq, bq, qb);
        hipFuncSetAttribute((const void*)main2_kernel,
                            hipFuncAttributeMaxDynamicSharedMemorySize, MAIN2_LDS);
        hipLaunchKernelGGL(main2_kernel, dim3(N_PTS / 128), dim3(256), MAIN2_LDS,
                           stream, feat, qb, k_s, vT, out);
    } else {
        hipFuncSetAttribute((const void*)main_kernel,
                            hipFuncAttributeMaxDynamicSharedMemorySize, MAIN_LDS);
        hipLaunchKernelGGL(main_kernel, dim3(N_PTS / 128), dim3(256), MAIN_LDS,
                           stream, feat, Wq, bq, k_s, vT, out);
    }
}

// Round 20
// 853.758 us; speedup vs baseline: 1.7481x; 1.0565x over previous
//
#include <hip/hip_runtime.h>
#include <hip/hip_bf16.h>

#define N_PTS  65536
#define DMODEL 256
#define MSAMP  1024

#define NW    64   // FPS waves = single-wave workgroups (all co-resident)
#define FPT   16   // points per lane: 65536 / (64 * 64)
#define FPP   8    // point PAIRS per lane (f32x2 packed math)
#define SLW   16   // u64s per slot line: 128B stride, one wave per line
#define NCAND 8    // candidates published per wave (+1 bound slot) — R10 proven

typedef short bf16x8_t __attribute__((ext_vector_type(8)));
typedef float f32x4_t  __attribute__((ext_vector_type(4)));
typedef float f32x2_t  __attribute__((ext_vector_type(2)));

__device__ __forceinline__ short f2bs(float f) {
    __hip_bfloat16 h = __float2bfloat16(f);   // RNE
    return *reinterpret_cast<short*>(&h);
}

__device__ __forceinline__ bf16x8_t cvt8(const float* p) {
    f32x4_t a = *(const f32x4_t*)(p);
    f32x4_t b = *(const f32x4_t*)(p + 4);
    bf16x8_t r;
#pragma unroll
    for (int i = 0; i < 4; i++) { r[i] = f2bs(a[i]); r[i + 4] = f2bs(b[i]); }
    return r;
}

// u64 max via f64 fmax (packs are positive f64 bit patterns; proven R5-R19)
__device__ __forceinline__ unsigned long long dmax64(unsigned long long a,
                                                     unsigned long long b) {
    double r = fmax(__longlong_as_double((long long)a),
                    __longlong_as_double((long long)b));
    return (unsigned long long)__double_as_longlong(r);
}

// ---- full-wave max via DPP (VALU pipe) — R16 proven ----------------------
__device__ __forceinline__ unsigned wave_umax_dpp(unsigned v) {
    unsigned t;
    t = __builtin_amdgcn_update_dpp(0, (int)v, 0x111, 0xF, 0xF, false); v = v > (unsigned)t ? v : (unsigned)t;
    t = __builtin_amdgcn_update_dpp(0, (int)v, 0x112, 0xF, 0xF, false); v = v > (unsigned)t ? v : (unsigned)t;
    t = __builtin_amdgcn_update_dpp(0, (int)v, 0x114, 0xF, 0xF, false); v = v > (unsigned)t ? v : (unsigned)t;
    t = __builtin_amdgcn_update_dpp(0, (int)v, 0x118, 0xF, 0xF, false); v = v > (unsigned)t ? v : (unsigned)t;
    t = __builtin_amdgcn_update_dpp(0, (int)v, 0x142, 0xF, 0xF, false); v = v > (unsigned)t ? v : (unsigned)t;
    t = __builtin_amdgcn_update_dpp(0, (int)v, 0x143, 0xF, 0xF, false); v = v > (unsigned)t ? v : (unsigned)t;
    return (unsigned)__builtin_amdgcn_readlane((int)v, 63);
}
// R18-proven wave-max of pack with unique-value fast path (bitwise exact).
__device__ __forceinline__ unsigned long long wave_maxpack(unsigned long long p) {
    unsigned hv = (unsigned)(p >> 32);
    unsigned lv = (unsigned)p;
    unsigned gv = wave_umax_dpp(hv);
    unsigned long long m = __ballot(hv == gv);
    unsigned gl;
    if (__popcll(m) == 1) {
        gl = (unsigned)__builtin_amdgcn_readlane((int)lv, (int)(__ffsll(m) - 1));
    } else {
        gl = wave_umax_dpp((hv == gv) ? lv : 0u);
    }
    return (((unsigned long long)gv) << 32) | gl;
}
// R20: guaranteed-readlane float broadcast from a wave-uniform (SGPR) lane.
__device__ __forceinline__ float bcast_lane_f(float v, int lane) {
    return __uint_as_float(
        (unsigned)__builtin_amdgcn_readlane((int)__float_as_uint(v), lane));
}

// ---------------------------------------------------------------------------
// Batched-candidate FPS — R18 skeleton (638us best). R20 change: the three
// winner-coordinate broadcasts use explicit readlane (ol is SGPR-uniform,
// from ballot+ffs) instead of __shfl, guaranteeing the SALU-cheap form
// instead of a possible ds_bpermute. Bitwise-identical semantics.
// ---------------------------------------------------------------------------
#pragma clang fp contract(off)
__global__ __launch_bounds__(64) void fps_kernel(
    const float*        __restrict__ xyz,      // (N,3) f32
    unsigned long long* __restrict__ slots,    // [2][NW][SLW] u64, zeroed per call
    int*                __restrict__ idx)      // (MSAMP) out
{
    const int l = threadIdx.x;       // 0..63
    const int g = blockIdx.x;        // 0..63
    const int base = g * (FPT * 64) + l;

    f32x2_t px2[FPP], py2[FPP], pz2[FPP], dd2[FPP];
    unsigned long long ivi[FPT];
    const float c0x = xyz[0], c0y = xyz[1], c0z = xyz[2];   // winner 0 = point 0
    {
        f32x2_t w0x = {c0x, c0x}, w0y = {c0y, c0y}, w0z = {c0z, c0z};
#pragma unroll
        for (int i = 0; i < FPP; i++) {
            int p0 = base + (2 * i) * 64;
            int p1 = base + (2 * i + 1) * 64;
            px2[i].x = xyz[3 * p0 + 0]; px2[i].y = xyz[3 * p1 + 0];
            py2[i].x = xyz[3 * p0 + 1]; py2[i].y = xyz[3 * p1 + 1];
            pz2[i].x = xyz[3 * p0 + 2]; pz2[i].y = xyz[3 * p1 + 2];
            ivi[2 * i]     = (unsigned long long)(0xFFFFu - (unsigned)p0);
            ivi[2 * i + 1] = (unsigned long long)(0xFFFFu - (unsigned)p1);
            f32x2_t dx = px2[i] - w0x, dy = py2[i] - w0y, dz = pz2[i] - w0z;
            f32x2_t d  = (dx * dx + dy * dy) + dz * dz;   // contract off: RN each op
            dd2[i].x = fminf(1e10f, d.x);
            dd2[i].y = fminf(1e10f, d.y);
        }
    }
    if (g == 0 && l == 0) idx[0] = 0;

    int total = 0, r = 0;
    while (total < MSAMP - 1) {
        ++r;
        unsigned long long pk[FPT];
#pragma unroll
        for (int i = 0; i < FPP; i++) {
            pk[2 * i]     = (((unsigned long long)__float_as_uint(dd2[i].x)) << 32) | ivi[2 * i];
            pk[2 * i + 1] = (((unsigned long long)__float_as_uint(dd2[i].y)) << 32) | ivi[2 * i + 1];
        }

        unsigned long long top[NCAND + 1];
        unsigned long long prev = ~0ull;            // matches no pack
#pragma unroll
        for (int t = 0; t < NCAND + 1; t++) {
            unsigned long long lm = 0;
#pragma unroll
            for (int i = 0; i < FPT; i++) {
                pk[i] = (pk[i] == prev) ? 0ull : pk[i];
                lm = dmax64(lm, pk[i]);
            }
            unsigned long long gt = wave_maxpack(lm);
            top[t] = gt;
            prev = gt;
        }

        const int ph = r & 1;
        const unsigned rt = (unsigned)(r & 0xFFFF);
        unsigned long long sv = top[0];
#pragma unroll
        for (int t = 1; t <= NCAND; t++) sv = (l == t) ? top[t] : sv;
        sv |= ((unsigned long long)rt) << 16;       // bits 16-31 free in packs
        if (l <= NCAND)
            __hip_atomic_store(slots + ((size_t)(ph * NW + g) * SLW + l), sv,
                               __ATOMIC_RELAXED, __HIP_MEMORY_SCOPE_AGENT);

        const unsigned long long* Q = slots + (size_t)ph * NW * SLW + (size_t)l * SLW;
        unsigned long long u[NCAND + 1];
        for (;;) {
            bool ok = true;
#pragma unroll
            for (int t = 0; t <= NCAND; t++) {
                u[t] = __hip_atomic_load(Q + t, __ATOMIC_RELAXED,
                                         __HIP_MEMORY_SCOPE_AGENT);
                ok &= (((unsigned)(u[t] >> 16) & 0xFFFFu) == rt);
            }
            if (__all(ok)) break;
            __builtin_amdgcn_s_sleep(2);
        }

        f32x2_t cv2[NCAND / 2], cx2[NCAND / 2], cy2[NCAND / 2], cz2[NCAND / 2];
        unsigned ici[NCAND];
#pragma unroll
        for (int c = 0; c < NCAND / 2; c++) {
            unsigned long long u0 = u[2 * c], u1 = u[2 * c + 1];
            cv2[c].x = __uint_as_float((unsigned)(u0 >> 32));
            cv2[c].y = __uint_as_float((unsigned)(u1 >> 32));
            ici[2 * c]     = (unsigned)(u0 & 0xFFFFu);
            ici[2 * c + 1] = (unsigned)(u1 & 0xFFFFu);
            int p0 = 0xFFFF - (int)ici[2 * c];
            int p1 = 0xFFFF - (int)ici[2 * c + 1];
            cx2[c].x = xyz[3 * p0 + 0]; cx2[c].y = xyz[3 * p1 + 0];
            cy2[c].x = xyz[3 * p0 + 1]; cy2[c].y = xyz[3 * p1 + 1];
            cz2[c].x = xyz[3 * p0 + 2]; cz2[c].y = xyz[3 * p1 + 2];
        }
        float mB = __uint_as_float(wave_umax_dpp((unsigned)(u[NCAND] >> 32)));

        int kk = 0;
        while (total < MSAMP - 1) {
            unsigned long long lb = 0;
#pragma unroll
            for (int c = 0; c < NCAND / 2; c++) {
                lb = dmax64(lb, (((unsigned long long)__float_as_uint(cv2[c].x)) << 32) | ici[2 * c]);
                lb = dmax64(lb, (((unsigned long long)__float_as_uint(cv2[c].y)) << 32) | ici[2 * c + 1]);
            }
            unsigned long long gb = wave_maxpack(lb);
            float gv = __uint_as_float((unsigned)(gb >> 32));
            if (kk > 0 && !(gv > mB)) break;     // strict >: exact vs unpublished

            int widx = 0xFFFF - (int)(gb & 0xFFFFu);
            if (g == 0 && l == 0) idx[total + 1] = widx;

            float sx = cx2[0].x, sy = cy2[0].x, sz = cz2[0].x;
#pragma unroll
            for (int c = 0; c < NCAND / 2; c++) {
                bool h0 = ((((unsigned long long)__float_as_uint(cv2[c].x)) << 32) | ici[2 * c]) == gb;
                bool h1 = ((((unsigned long long)__float_as_uint(cv2[c].y)) << 32) | ici[2 * c + 1]) == gb;
                sx = h0 ? cx2[c].x : sx; sx = h1 ? cx2[c].y : sx;
                sy = h0 ? cy2[c].x : sy; sy = h1 ? cy2[c].y : sy;
                sz = h0 ? cz2[c].x : sz; sz = h1 ? cz2[c].y : sz;
            }
            unsigned long long mo = __ballot(lb == gb);
            int ol = (int)(__ffsll((unsigned long long)mo) - 1);   // SGPR-uniform
            float wx = bcast_lane_f(sx, ol);
            float wy = bcast_lane_f(sy, ol);
            float wz = bcast_lane_f(sz, ol);

            f32x2_t wx2 = {wx, wx}, wy2 = {wy, wy}, wz2 = {wz, wz};
#pragma unroll
            for (int c = 0; c < NCAND / 2; c++) {
                f32x2_t dx = cx2[c] - wx2, dy = cy2[c] - wy2, dz = cz2[c] - wz2;
                f32x2_t d  = (dx * dx + dy * dy) + dz * dz;
                cv2[c].x = fminf(cv2[c].x, d.x);
                cv2[c].y = fminf(cv2[c].y, d.y);
            }
#pragma unroll
            for (int i = 0; i < FPP; i++) {
                f32x2_t dx = px2[i] - wx2, dy = py2[i] - wy2, dz = pz2[i] - wz2;
                f32x2_t d  = (dx * dx + dy * dy) + dz * dz;
                dd2[i].x = fminf(dd2[i].x, d.x);
                dd2[i].y = fminf(dd2[i].y, d.y);
            }

            total++; kk++;
        }
    }
}
#pragma clang fp contract(on)

// ---------------------------------------------------------------------------
// Gather + K/V projection in f32; outputs bf16.   [R10 verbatim, proven]
// ---------------------------------------------------------------------------
__global__ __launch_bounds__(256) void kv_kernel(
    const float* __restrict__ feat,
    const float* __restrict__ Wk, const float* __restrict__ bk,
    const float* __restrict__ Wv, const float* __restrict__ bv,
    const int* __restrict__ idx,
    unsigned short* __restrict__ k_s,   // (MSAMP, DMODEL) bf16, * 1/16
    unsigned short* __restrict__ vT)    // (DMODEL, MSAMP) bf16
{
    __shared__ float fl[4][DMODEL];
    const int t  = threadIdx.x;
    const int j0 = blockIdx.x * 4;
    {
        int jj = t >> 6;
        int e  = (t & 63) * 4;
        int src = idx[j0 + jj];
        f32x4_t v = *(const f32x4_t*)(feat + (size_t)src * DMODEL + e);
        fl[jj][e + 0] = v[0];
        fl[jj][e + 1] = v[1];
        fl[jj][e + 2] = v[2];
        fl[jj][e + 3] = v[3];
    }
    __syncthreads();

    float ak[4] = {0.f, 0.f, 0.f, 0.f};
    float av[4] = {0.f, 0.f, 0.f, 0.f};
    const float* wkr = Wk + (size_t)t * DMODEL;
    const float* wvr = Wv + (size_t)t * DMODEL;
#pragma unroll 4
    for (int in = 0; in < DMODEL; in += 4) {
        f32x4_t ku = *(const f32x4_t*)(wkr + in);
        f32x4_t vu = *(const f32x4_t*)(wvr + in);
#pragma unroll
        for (int jj = 0; jj < 4; jj++) {
            ak[jj] = fmaf(fl[jj][in + 0], ku[0], ak[jj]);
            ak[jj] = fmaf(fl[jj][in + 1], ku[1], ak[jj]);
            ak[jj] = fmaf(fl[jj][in + 2], ku[2], ak[jj]);
            ak[jj] = fmaf(fl[jj][in + 3], ku[3], ak[jj]);
            av[jj] = fmaf(fl[jj][in + 0], vu[0], av[jj]);
            av[jj] = fmaf(fl[jj][in + 1], vu[1], av[jj]);
            av[jj] = fmaf(fl[jj][in + 2], vu[2], av[jj]);
            av[jj] = fmaf(fl[jj][in + 3], vu[3], av[jj]);
        }
    }
    float bkv = bk[t];
    float bvv = bv[t];
#pragma unroll
    for (int jj = 0; jj < 4; jj++) {
        k_s[(unsigned)(j0 + jj) * DMODEL + t] = (unsigned short)f2bs((ak[jj] + bkv) * 0.0625f);
        vT[(unsigned)t * MSAMP + (j0 + jj)]   = (unsigned short)f2bs(av[jj] + bvv);
    }
}

// ---------------------------------------------------------------------------
// Fused q -> w -> res -> concat. 128-row tile, 4 waves (2 row x 2 col), MFMA
// 16x16x32 bf16, double-buffered wlds.   [R14 verbatim — best measured tail]
// ---------------------------------------------------------------------------
#define QS  264
#define WSR 136
#define RS  258
#define WBUF (128 * WSR)                       // u16 elems per wlds buffer
#define MAIN_LDS (128 * QS * 2 + 2 * WBUF * 2) // 137216 B

__global__ __launch_bounds__(256, 1) void main_kernel(
    const float* __restrict__ feat,
    const float* __restrict__ Wq, const float* __restrict__ bq,
    const unsigned short* __restrict__ k_s,
    const unsigned short* __restrict__ vT,
    float* __restrict__ out)
{
    extern __shared__ char smem[];
    unsigned short* qlds = (unsigned short*)smem;
    unsigned short* wlds = (unsigned short*)(smem + 128 * QS * 2);

    const int tid  = threadIdx.x;
    const int ln   = tid & 63;
    const int wid  = tid >> 6;
    const int wr   = wid & 1;
    const int wc   = wid >> 1;
    const int r0   = blockIdx.x * 128;
    const int lrow = ln & 15;
    const int lk   = (ln >> 4) * 8;
    const int crow = (ln >> 4) * 4;

    const f32x4_t fzero = {0.f, 0.f, 0.f, 0.f};

    // ---- phase 1: q = feat @ Wq^T + bq -> bf16 in qlds ----
    f32x4_t qa[4][8];
#pragma unroll
    for (int m = 0; m < 4; m++)
#pragma unroll
        for (int n = 0; n < 8; n++) qa[m][n] = fzero;

#pragma unroll
    for (int kb = 0; kb < DMODEL; kb += 32) {
        bf16x8_t A[4], B[8];
#pragma unroll
        for (int m = 0; m < 4; m++)
            A[m] = cvt8(feat + (size_t)(r0 + wr * 64 + m * 16 + lrow) * DMODEL + kb + lk);
#pragma unroll
        for (int n = 0; n < 8; n++)
            B[n] = cvt8(Wq + (size_t)(wc * 128 + n * 16 + lrow) * DMODEL + kb + lk);
#pragma unroll
        for (int m = 0; m < 4; m++)
#pragma unroll
            for (int n = 0; n < 8; n++)
                qa[m][n] = __builtin_amdgcn_mfma_f32_16x16x32_bf16(
                    A[m], B[n], qa[m][n], 0, 0, 0);
    }
#pragma unroll
    for (int n = 0; n < 8; n++) {
        float bqv = bq[wc * 128 + n * 16 + lrow];
#pragma unroll
        for (int m = 0; m < 4; m++)
#pragma unroll
            for (int r = 0; r < 4; r++)
                qlds[(wr * 64 + m * 16 + crow + r) * QS + wc * 128 + n * 16 + lrow] =
                    (unsigned short)f2bs(qa[m][n][r] + bqv);
    }
    __syncthreads();

    // ---- phase 2: dbuf flash loop ----
    f32x4_t racc[4][8];
#pragma unroll
    for (int m = 0; m < 4; m++)
#pragma unroll
        for (int n = 0; n < 8; n++) racc[m][n] = fzero;

    // prologue: w(0) -> wlds buf 0
    {
        f32x4_t wa[4][4];
#pragma unroll
        for (int m = 0; m < 4; m++)
#pragma unroll
            for (int n = 0; n < 4; n++) wa[m][n] = fzero;
#pragma unroll
        for (int kb = 0; kb < DMODEL; kb += 32) {
            bf16x8_t A[4], B[4];
#pragma unroll
            for (int m = 0; m < 4; m++)
                A[m] = *(const bf16x8_t*)(qlds + (wr * 64 + m * 16 + lrow) * QS + kb + lk);
#pragma unroll
            for (int n = 0; n < 4; n++)
                B[n] = *(const bf16x8_t*)(k_s +
                    (size_t)(wc * 64 + n * 16 + lrow) * DMODEL + kb + lk);
#pragma unroll
            for (int m = 0; m < 4; m++)
#pragma unroll
                for (int n = 0; n < 4; n++)
                    wa[m][n] = __builtin_amdgcn_mfma_f32_16x16x32_bf16(
                        A[m], B[n], wa[m][n], 0, 0, 0);
        }
#pragma unroll
        for (int m = 0; m < 4; m++)
#pragma unroll
            for (int n = 0; n < 4; n++)
#pragma unroll
                for (int r = 0; r < 4; r++)
                    wlds[(wr * 64 + m * 16 + crow + r) * WSR + wc * 64 + n * 16 + lrow] =
                        (unsigned short)f2bs(wa[m][n][r]);
    }
    __syncthreads();

    for (int jb = 0; jb < 8; jb++) {
        const int cur = jb & 1;
        unsigned short* wcur = wlds + cur * WBUF;
        unsigned short* wnxt = wlds + (cur ^ 1) * WBUF;

        if (jb < 7) {
            f32x4_t wa[4][4];
#pragma unroll
            for (int m = 0; m < 4; m++)
#pragma unroll
                for (int n = 0; n < 4; n++) wa[m][n] = fzero;
#pragma unroll
            for (int kb = 0; kb < DMODEL; kb += 32) {
                bf16x8_t A[4], B[4];
#pragma unroll
                for (int m = 0; m < 4; m++)
                    A[m] = *(const bf16x8_t*)(qlds + (wr * 64 + m * 16 + lrow) * QS + kb + lk);
#pragma unroll
                for (int n = 0; n < 4; n++)
                    B[n] = *(const bf16x8_t*)(k_s +
                        (size_t)((jb + 1) * 128 + wc * 64 + n * 16 + lrow) * DMODEL + kb + lk);
#pragma unroll
                for (int m = 0; m < 4; m++)
#pragma unroll
                    for (int n = 0; n < 4; n++)
                        wa[m][n] = __builtin_amdgcn_mfma_f32_16x16x32_bf16(
                            A[m], B[n], wa[m][n], 0, 0, 0);
            }
#pragma unroll
            for (int m = 0; m < 4; m++)
#pragma unroll
                for (int n = 0; n < 4; n++)
#pragma unroll
                    for (int r = 0; r < 4; r++)
                        wnxt[(wr * 64 + m * 16 + crow + r) * WSR + wc * 64 + n * 16 + lrow] =
                            (unsigned short)f2bs(wa[m][n][r]);
        }

#pragma unroll
        for (int kb2 = 0; kb2 < 128; kb2 += 32) {
            bf16x8_t A[4], B[8];
#pragma unroll
            for (int m = 0; m < 4; m++)
                A[m] = *(const bf16x8_t*)(wcur + (wr * 64 + m * 16 + lrow) * WSR + kb2 + lk);
#pragma unroll
            for (int n = 0; n < 8; n++)
                B[n] = *(const bf16x8_t*)(vT +
                    (size_t)(wc * 128 + n * 16 + lrow) * MSAMP + jb * 128 + kb2 + lk);
#pragma unroll
            for (int m = 0; m < 4; m++)
#pragma unroll
                for (int n = 0; n < 8; n++)
                    racc[m][n] = __builtin_amdgcn_mfma_f32_16x16x32_bf16(
                        A[m], B[n], racc[m][n], 0, 0, 0);
        }
        __syncthreads();
    }

    // ---- phase 3: epilogue, f32 res -> LDS, coalesced f32 [res|feat] store ----
    float* rlds = (float*)smem;   // qlds/wlds dead now (final barrier above)
#pragma unroll
    for (int m = 0; m < 4; m++)
#pragma unroll
        for (int n = 0; n < 8; n++)
#pragma unroll
            for (int r = 0; r < 4; r++)
                rlds[(wr * 64 + m * 16 + crow + r) * RS + wc * 128 + n * 16 + lrow] =
                    racc[m][n][r];
    __syncthreads();

#pragma unroll
    for (int base = 0; base < 128; base += 4) {
        int row = base + wid;
        f32x4_t a = *(const f32x4_t*)(rlds + row * RS + ln * 4);
        f32x4_t b = *(const f32x4_t*)(feat + (size_t)(r0 + row) * DMODEL + ln * 4);
        *(f32x4_t*)(out + (size_t)(r0 + row) * 512 + ln * 4)       = a;
        *(f32x4_t*)(out + (size_t)(r0 + row) * 512 + 256 + ln * 4) = b;
    }
}

// ---------------------------------------------------------------------------
extern "C" void kernel_launch(void* const* d_in, const int* in_sizes, int n_in,
                              void* d_out, int out_size, void* d_ws, size_t ws_size,
                              hipStream_t stream) {
    const float* p_xyz = (const float*)d_in[0];
    const float* feat  = (const float*)d_in[1];
    const float* Wq    = (const float*)d_in[2];
    const float* bq    = (const float*)d_in[3];
    const float* Wk    = (const float*)d_in[4];
    const float* bk    = (const float*)d_in[5];
    const float* Wv    = (const float*)d_in[6];
    const float* bv    = (const float*)d_in[7];
    float* out = (float*)d_out;

    char* ws = (char*)d_ws;
    unsigned long long* slots = (unsigned long long*)ws;                //  16 KB [2][NW][SLW]
    int*                idx   = (int*)(ws + 16384);                     //   4 KB
    unsigned short*     k_s   = (unsigned short*)(ws + 32768);          // 512 KB
    unsigned short*     vT    = (unsigned short*)(ws + 32768 + 524288); // 512 KB

    hipMemsetAsync(d_ws, 0, 16384, stream);   // invalidate slots every call

    hipLaunchKernelGGL(fps_kernel, dim3(NW), dim3(64), 0, stream,
                       p_xyz, slots, idx);
    hipLaunchKernelGGL(kv_kernel, dim3(MSAMP / 4), dim3(256), 0, stream,
                       feat, Wk, bk, Wv, bv, idx, k_s, vT);
    hipFuncSetAttribute((const void*)main_kernel,
                        hipFuncAttributeMaxDynamicSharedMemorySize, MAIN_LDS);
    hipLaunchKernelGGL(main_kernel, dim3(N_PTS / 128), dim3(256), MAIN_LDS, stream,
                       feat, Wq, bq, k_s, vT, out);
}

// Round 22
// 853.327 us; speedup vs baseline: 1.7490x; 1.0005x over previous
//
#include <hip/hip_runtime.h>
#include <hip/hip_bf16.h>

#define N_PTS  65536
#define DMODEL 256
#define MSAMP  1024

#define NW    64   // FPS waves = single-wave workgroups (all co-resident)
#define FPT   16   // points per lane: 65536 / (64 * 64)
#define FPP   8    // point PAIRS per lane (f32x2 packed math)
#define SLW   16   // u64s per slot line: 128B stride, one wave per line
#define NCAND 8    // candidates published per wave (+1 bound slot) — R10 proven

typedef short bf16x8_t __attribute__((ext_vector_type(8)));
typedef float f32x4_t  __attribute__((ext_vector_type(4)));
typedef float f32x2_t  __attribute__((ext_vector_type(2)));

__device__ __forceinline__ short f2bs(float f) {
    __hip_bfloat16 h = __float2bfloat16(f);   // RNE
    return *reinterpret_cast<short*>(&h);
}

__device__ __forceinline__ bf16x8_t cvt8(const float* p) {
    f32x4_t a = *(const f32x4_t*)(p);
    f32x4_t b = *(const f32x4_t*)(p + 4);
    bf16x8_t r;
#pragma unroll
    for (int i = 0; i < 4; i++) { r[i] = f2bs(a[i]); r[i + 4] = f2bs(b[i]); }
    return r;
}

// u64 max via f64 fmax (packs are positive f64 bit patterns; proven R5-R20)
__device__ __forceinline__ unsigned long long dmax64(unsigned long long a,
                                                     unsigned long long b) {
    double r = fmax(__longlong_as_double((long long)a),
                    __longlong_as_double((long long)b));
    return (unsigned long long)__double_as_longlong(r);
}

// ---- full-wave max via DPP (VALU pipe) — R16 proven ----------------------
__device__ __forceinline__ unsigned wave_umax_dpp(unsigned v) {
    unsigned t;
    t = __builtin_amdgcn_update_dpp(0, (int)v, 0x111, 0xF, 0xF, false); v = v > (unsigned)t ? v : (unsigned)t;
    t = __builtin_amdgcn_update_dpp(0, (int)v, 0x112, 0xF, 0xF, false); v = v > (unsigned)t ? v : (unsigned)t;
    t = __builtin_amdgcn_update_dpp(0, (int)v, 0x114, 0xF, 0xF, false); v = v > (unsigned)t ? v : (unsigned)t;
    t = __builtin_amdgcn_update_dpp(0, (int)v, 0x118, 0xF, 0xF, false); v = v > (unsigned)t ? v : (unsigned)t;
    t = __builtin_amdgcn_update_dpp(0, (int)v, 0x142, 0xF, 0xF, false); v = v > (unsigned)t ? v : (unsigned)t;
    t = __builtin_amdgcn_update_dpp(0, (int)v, 0x143, 0xF, 0xF, false); v = v > (unsigned)t ? v : (unsigned)t;
    return (unsigned)__builtin_amdgcn_readlane((int)v, 63);
}
// R18-proven wave-max of pack with unique-value fast path (bitwise exact).
__device__ __forceinline__ unsigned long long wave_maxpack(unsigned long long p) {
    unsigned hv = (unsigned)(p >> 32);
    unsigned lv = (unsigned)p;
    unsigned gv = wave_umax_dpp(hv);
    unsigned long long m = __ballot(hv == gv);
    unsigned gl;
    if (__popcll(m) == 1) {
        gl = (unsigned)__builtin_amdgcn_readlane((int)lv, (int)(__ffsll(m) - 1));
    } else {
        gl = wave_umax_dpp((hv == gv) ? lv : 0u);
    }
    return (((unsigned long long)gv) << 32) | gl;
}
// R20: guaranteed-readlane float broadcast from a wave-uniform (SGPR) lane.
__device__ __forceinline__ float bcast_lane_f(float v, int lane) {
    return __uint_as_float(
        (unsigned)__builtin_amdgcn_readlane((int)__float_as_uint(v), lane));
}

// ---------------------------------------------------------------------------
// Batched-candidate FPS — R20 verbatim (measured 623us). NCAND=8, DPP
// reduces, packed f32x2 distance math, readlane winner broadcasts.
// Exact numpy arithmetic (per-op RN f32, ((dx^2+dy^2)+dz^2), no FMA) and
// first-index argmax tie-break via (value, 0xFFFF-idx) packing.
// ---------------------------------------------------------------------------
#pragma clang fp contract(off)
__global__ __launch_bounds__(64) void fps_kernel(
    const float*        __restrict__ xyz,      // (N,3) f32
    unsigned long long* __restrict__ slots,    // [2][NW][SLW] u64, zeroed per call
    int*                __restrict__ idx)      // (MSAMP) out
{
    const int l = threadIdx.x;       // 0..63
    const int g = blockIdx.x;        // 0..63
    const int base = g * (FPT * 64) + l;

    f32x2_t px2[FPP], py2[FPP], pz2[FPP], dd2[FPP];
    unsigned long long ivi[FPT];
    const float c0x = xyz[0], c0y = xyz[1], c0z = xyz[2];   // winner 0 = point 0
    {
        f32x2_t w0x = {c0x, c0x}, w0y = {c0y, c0y}, w0z = {c0z, c0z};
#pragma unroll
        for (int i = 0; i < FPP; i++) {
            int p0 = base + (2 * i) * 64;
            int p1 = base + (2 * i + 1) * 64;
            px2[i].x = xyz[3 * p0 + 0]; px2[i].y = xyz[3 * p1 + 0];
            py2[i].x = xyz[3 * p0 + 1]; py2[i].y = xyz[3 * p1 + 1];
            pz2[i].x = xyz[3 * p0 + 2]; pz2[i].y = xyz[3 * p1 + 2];
            ivi[2 * i]     = (unsigned long long)(0xFFFFu - (unsigned)p0);
            ivi[2 * i + 1] = (unsigned long long)(0xFFFFu - (unsigned)p1);
            f32x2_t dx = px2[i] - w0x, dy = py2[i] - w0y, dz = pz2[i] - w0z;
            f32x2_t d  = (dx * dx + dy * dy) + dz * dz;   // contract off: RN each op
            dd2[i].x = fminf(1e10f, d.x);
            dd2[i].y = fminf(1e10f, d.y);
        }
    }
    if (g == 0 && l == 0) idx[0] = 0;

    int total = 0, r = 0;
    while (total < MSAMP - 1) {
        ++r;
        unsigned long long pk[FPT];
#pragma unroll
        for (int i = 0; i < FPP; i++) {
            pk[2 * i]     = (((unsigned long long)__float_as_uint(dd2[i].x)) << 32) | ivi[2 * i];
            pk[2 * i + 1] = (((unsigned long long)__float_as_uint(dd2[i].y)) << 32) | ivi[2 * i + 1];
        }

        unsigned long long top[NCAND + 1];
        unsigned long long prev = ~0ull;            // matches no pack
#pragma unroll
        for (int t = 0; t < NCAND + 1; t++) {
            unsigned long long lm = 0;
#pragma unroll
            for (int i = 0; i < FPT; i++) {
                pk[i] = (pk[i] == prev) ? 0ull : pk[i];
                lm = dmax64(lm, pk[i]);
            }
            unsigned long long gt = wave_maxpack(lm);
            top[t] = gt;
            prev = gt;
        }

        const int ph = r & 1;
        const unsigned rt = (unsigned)(r & 0xFFFF);
        unsigned long long sv = top[0];
#pragma unroll
        for (int t = 1; t <= NCAND; t++) sv = (l == t) ? top[t] : sv;
        sv |= ((unsigned long long)rt) << 16;       // bits 16-31 free in packs
        if (l <= NCAND)
            __hip_atomic_store(slots + ((size_t)(ph * NW + g) * SLW + l), sv,
                               __ATOMIC_RELAXED, __HIP_MEMORY_SCOPE_AGENT);

        const unsigned long long* Q = slots + (size_t)ph * NW * SLW + (size_t)l * SLW;
        unsigned long long u[NCAND + 1];
        for (;;) {
            bool ok = true;
#pragma unroll
            for (int t = 0; t <= NCAND; t++) {
                u[t] = __hip_atomic_load(Q + t, __ATOMIC_RELAXED,
                                         __HIP_MEMORY_SCOPE_AGENT);
                ok &= (((unsigned)(u[t] >> 16) & 0xFFFFu) == rt);
            }
            if (__all(ok)) break;
            __builtin_amdgcn_s_sleep(2);
        }

        f32x2_t cv2[NCAND / 2], cx2[NCAND / 2], cy2[NCAND / 2], cz2[NCAND / 2];
        unsigned ici[NCAND];
#pragma unroll
        for (int c = 0; c < NCAND / 2; c++) {
            unsigned long long u0 = u[2 * c], u1 = u[2 * c + 1];
            cv2[c].x = __uint_as_float((unsigned)(u0 >> 32));
            cv2[c].y = __uint_as_float((unsigned)(u1 >> 32));
            ici[2 * c]     = (unsigned)(u0 & 0xFFFFu);
            ici[2 * c + 1] = (unsigned)(u1 & 0xFFFFu);
            int p0 = 0xFFFF - (int)ici[2 * c];
            int p1 = 0xFFFF - (int)ici[2 * c + 1];
            cx2[c].x = xyz[3 * p0 + 0]; cx2[c].y = xyz[3 * p1 + 0];
            cy2[c].x = xyz[3 * p0 + 1]; cy2[c].y = xyz[3 * p1 + 1];
            cz2[c].x = xyz[3 * p0 + 2]; cz2[c].y = xyz[3 * p1 + 2];
        }
        float mB = __uint_as_float(wave_umax_dpp((unsigned)(u[NCAND] >> 32)));

        int kk = 0;
        while (total < MSAMP - 1) {
            unsigned long long lb = 0;
#pragma unroll
            for (int c = 0; c < NCAND / 2; c++) {
                lb = dmax64(lb, (((unsigned long long)__float_as_uint(cv2[c].x)) << 32) | ici[2 * c]);
                lb = dmax64(lb, (((unsigned long long)__float_as_uint(cv2[c].y)) << 32) | ici[2 * c + 1]);
            }
            unsigned long long gb = wave_maxpack(lb);
            float gv = __uint_as_float((unsigned)(gb >> 32));
            if (kk > 0 && !(gv > mB)) break;     // strict >: exact vs unpublished

            int widx = 0xFFFF - (int)(gb & 0xFFFFu);
            if (g == 0 && l == 0) idx[total + 1] = widx;

            float sx = cx2[0].x, sy = cy2[0].x, sz = cz2[0].x;
#pragma unroll
            for (int c = 0; c < NCAND / 2; c++) {
                bool h0 = ((((unsigned long long)__float_as_uint(cv2[c].x)) << 32) | ici[2 * c]) == gb;
                bool h1 = ((((unsigned long long)__float_as_uint(cv2[c].y)) << 32) | ici[2 * c + 1]) == gb;
                sx = h0 ? cx2[c].x : sx; sx = h1 ? cx2[c].y : sx;
                sy = h0 ? cy2[c].x : sy; sy = h1 ? cy2[c].y : sy;
                sz = h0 ? cz2[c].x : sz; sz = h1 ? cz2[c].y : sz;
            }
            unsigned long long mo = __ballot(lb == gb);
            int ol = (int)(__ffsll((unsigned long long)mo) - 1);   // SGPR-uniform
            float wx = bcast_lane_f(sx, ol);
            float wy = bcast_lane_f(sy, ol);
            float wz = bcast_lane_f(sz, ol);

            f32x2_t wx2 = {wx, wx}, wy2 = {wy, wy}, wz2 = {wz, wz};
#pragma unroll
            for (int c = 0; c < NCAND / 2; c++) {
                f32x2_t dx = cx2[c] - wx2, dy = cy2[c] - wy2, dz = cz2[c] - wz2;
                f32x2_t d  = (dx * dx + dy * dy) + dz * dz;
                cv2[c].x = fminf(cv2[c].x, d.x);
                cv2[c].y = fminf(cv2[c].y, d.y);
            }
#pragma unroll
            for (int i = 0; i < FPP; i++) {
                f32x2_t dx = px2[i] - wx2, dy = py2[i] - wy2, dz = pz2[i] - wz2;
                f32x2_t d  = (dx * dx + dy * dy) + dz * dz;
                dd2[i].x = fminf(dd2[i].x, d.x);
                dd2[i].y = fminf(dd2[i].y, d.y);
            }

            total++; kk++;
        }
    }
}
#pragma clang fp contract(on)

// ---------------------------------------------------------------------------
// Gather + K/V projection in f32; outputs bf16.   [R10 verbatim, proven]
// ---------------------------------------------------------------------------
__global__ __launch_bounds__(256) void kv_kernel(
    const float* __restrict__ feat,
    const float* __restrict__ Wk, const float* __restrict__ bk,
    const float* __restrict__ Wv, const float* __restrict__ bv,
    const int* __restrict__ idx,
    unsigned short* __restrict__ k_s,   // (MSAMP, DMODEL) bf16, * 1/16
    unsigned short* __restrict__ vT)    // (DMODEL, MSAMP) bf16
{
    __shared__ float fl[4][DMODEL];
    const int t  = threadIdx.x;
    const int j0 = blockIdx.x * 4;
    {
        int jj = t >> 6;
        int e  = (t & 63) * 4;
        int src = idx[j0 + jj];
        f32x4_t v = *(const f32x4_t*)(feat + (size_t)src * DMODEL + e);
        fl[jj][e + 0] = v[0];
        fl[jj][e + 1] = v[1];
        fl[jj][e + 2] = v[2];
        fl[jj][e + 3] = v[3];
    }
    __syncthreads();

    float ak[4] = {0.f, 0.f, 0.f, 0.f};
    float av[4] = {0.f, 0.f, 0.f, 0.f};
    const float* wkr = Wk + (size_t)t * DMODEL;
    const float* wvr = Wv + (size_t)t * DMODEL;
#pragma unroll 4
    for (int in = 0; in < DMODEL; in += 4) {
        f32x4_t ku = *(const f32x4_t*)(wkr + in);
        f32x4_t vu = *(const f32x4_t*)(wvr + in);
#pragma unroll
        for (int jj = 0; jj < 4; jj++) {
            ak[jj] = fmaf(fl[jj][in + 0], ku[0], ak[jj]);
            ak[jj] = fmaf(fl[jj][in + 1], ku[1], ak[jj]);
            ak[jj] = fmaf(fl[jj][in + 2], ku[2], ak[jj]);
            ak[jj] = fmaf(fl[jj][in + 3], ku[3], ak[jj]);
            av[jj] = fmaf(fl[jj][in + 0], vu[0], av[jj]);
            av[jj] = fmaf(fl[jj][in + 1], vu[1], av[jj]);
            av[jj] = fmaf(fl[jj][in + 2], vu[2], av[jj]);
            av[jj] = fmaf(fl[jj][in + 3], vu[3], av[jj]);
        }
    }
    float bkv = bk[t];
    float bvv = bv[t];
#pragma unroll
    for (int jj = 0; jj < 4; jj++) {
        k_s[(unsigned)(j0 + jj) * DMODEL + t] = (unsigned short)f2bs((ak[jj] + bkv) * 0.0625f);
        vT[(unsigned)t * MSAMP + (j0 + jj)]   = (unsigned short)f2bs(av[jj] + bvv);
    }
}

// ---------------------------------------------------------------------------
// Fused q -> w -> res -> concat. 128-row tile, 4 waves (2 row x 2 col), MFMA
// 16x16x32 bf16, double-buffered wlds.   [R14 verbatim — best measured tail]
// ---------------------------------------------------------------------------
#define QS  264
#define WSR 136
#define RS  258
#define WBUF (128 * WSR)                       // u16 elems per wlds buffer
#define MAIN_LDS (128 * QS * 2 + 2 * WBUF * 2) // 137216 B

__global__ __launch_bounds__(256, 1) void main_kernel(
    const float* __restrict__ feat,
    const float* __restrict__ Wq, const float* __restrict__ bq,
    const unsigned short* __restrict__ k_s,
    const unsigned short* __restrict__ vT,
    float* __restrict__ out)
{
    extern __shared__ char smem[];
    unsigned short* qlds = (unsigned short*)smem;
    unsigned short* wlds = (unsigned short*)(smem + 128 * QS * 2);

    const int tid  = threadIdx.x;
    const int ln   = tid & 63;
    const int wid  = tid >> 6;
    const int wr   = wid & 1;
    const int wc   = wid >> 1;
    const int r0   = blockIdx.x * 128;
    const int lrow = ln & 15;
    const int lk   = (ln >> 4) * 8;
    const int crow = (ln >> 4) * 4;

    const f32x4_t fzero = {0.f, 0.f, 0.f, 0.f};

    // ---- phase 1: q = feat @ Wq^T + bq -> bf16 in qlds ----
    f32x4_t qa[4][8];
#pragma unroll
    for (int m = 0; m < 4; m++)
#pragma unroll
        for (int n = 0; n < 8; n++) qa[m][n] = fzero;

#pragma unroll
    for (int kb = 0; kb < DMODEL; kb += 32) {
        bf16x8_t A[4], B[8];
#pragma unroll
        for (int m = 0; m < 4; m++)
            A[m] = cvt8(feat + (size_t)(r0 + wr * 64 + m * 16 + lrow) * DMODEL + kb + lk);
#pragma unroll
        for (int n = 0; n < 8; n++)
            B[n] = cvt8(Wq + (size_t)(wc * 128 + n * 16 + lrow) * DMODEL + kb + lk);
#pragma unroll
        for (int m = 0; m < 4; m++)
#pragma unroll
            for (int n = 0; n < 8; n++)
                qa[m][n] = __builtin_amdgcn_mfma_f32_16x16x32_bf16(
                    A[m], B[n], qa[m][n], 0, 0, 0);
    }
#pragma unroll
    for (int n = 0; n < 8; n++) {
        float bqv = bq[wc * 128 + n * 16 + lrow];
#pragma unroll
        for (int m = 0; m < 4; m++)
#pragma unroll
            for (int r = 0; r < 4; r++)
                qlds[(wr * 64 + m * 16 + crow + r) * QS + wc * 128 + n * 16 + lrow] =
                    (unsigned short)f2bs(qa[m][n][r] + bqv);
    }
    __syncthreads();

    // ---- phase 2: dbuf flash loop ----
    f32x4_t racc[4][8];
#pragma unroll
    for (int m = 0; m < 4; m++)
#pragma unroll
        for (int n = 0; n < 8; n++) racc[m][n] = fzero;

    // prologue: w(0) -> wlds buf 0
    {
        f32x4_t wa[4][4];
#pragma unroll
        for (int m = 0; m < 4; m++)
#pragma unroll
            for (int n = 0; n < 4; n++) wa[m][n] = fzero;
#pragma unroll
        for (int kb = 0; kb < DMODEL; kb += 32) {
            bf16x8_t A[4], B[4];
#pragma unroll
            for (int m = 0; m < 4; m++)
                A[m] = *(const bf16x8_t*)(qlds + (wr * 64 + m * 16 + lrow) * QS + kb + lk);
#pragma unroll
            for (int n = 0; n < 4; n++)
                B[n] = *(const bf16x8_t*)(k_s +
                    (size_t)(wc * 64 + n * 16 + lrow) * DMODEL + kb + lk);
#pragma unroll
            for (int m = 0; m < 4; m++)
#pragma unroll
                for (int n = 0; n < 4; n++)
                    wa[m][n] = __builtin_amdgcn_mfma_f32_16x16x32_bf16(
                        A[m], B[n], wa[m][n], 0, 0, 0);
        }
#pragma unroll
        for (int m = 0; m < 4; m++)
#pragma unroll
            for (int n = 0; n < 4; n++)
#pragma unroll
                for (int r = 0; r < 4; r++)
                    wlds[(wr * 64 + m * 16 + crow + r) * WSR + wc * 64 + n * 16 + lrow] =
                        (unsigned short)f2bs(wa[m][n][r]);
    }
    __syncthreads();

    for (int jb = 0; jb < 8; jb++) {
        const int cur = jb & 1;
        unsigned short* wcur = wlds + cur * WBUF;
        unsigned short* wnxt = wlds + (cur ^ 1) * WBUF;

        if (jb < 7) {
            f32x4_t wa[4][4];
#pragma unroll
            for (int m = 0; m < 4; m++)
#pragma unroll
                for (int n = 0; n < 4; n++) wa[m][n] = fzero;
#pragma unroll
            for (int kb = 0; kb < DMODEL; kb += 32) {
                bf16x8_t A[4], B[4];
#pragma unroll
                for (int m = 0; m < 4; m++)
                    A[m] = *(const bf16x8_t*)(qlds + (wr * 64 + m * 16 + lrow) * QS + kb + lk);
#pragma unroll
                for (int n = 0; n < 4; n++)
                    B[n] = *(const bf16x8_t*)(k_s +
                        (size_t)((jb + 1) * 128 + wc * 64 + n * 16 + lrow) * DMODEL + kb + lk);
#pragma unroll
                for (int m = 0; m < 4; m++)
#pragma unroll
                    for (int n = 0; n < 4; n++)
                        wa[m][n] = __builtin_amdgcn_mfma_f32_16x16x32_bf16(
                            A[m], B[n], wa[m][n], 0, 0, 0);
            }
#pragma unroll
            for (int m = 0; m < 4; m++)
#pragma unroll
                for (int n = 0; n < 4; n++)
#pragma unroll
                    for (int r = 0; r < 4; r++)
                        wnxt[(wr * 64 + m * 16 + crow + r) * WSR + wc * 64 + n * 16 + lrow] =
                            (unsigned short)f2bs(wa[m][n][r]);
        }

#pragma unroll
        for (int kb2 = 0; kb2 < 128; kb2 += 32) {
            bf16x8_t A[4], B[8];
#pragma unroll
            for (int m = 0; m < 4; m++)
                A[m] = *(const bf16x8_t*)(wcur + (wr * 64 + m * 16 + lrow) * WSR + kb2 + lk);
#pragma unroll
            for (int n = 0; n < 8; n++)
                B[n] = *(const bf16x8_t*)(vT +
                    (size_t)(wc * 128 + n * 16 + lrow) * MSAMP + jb * 128 + kb2 + lk);
#pragma unroll
            for (int m = 0; m < 4; m++)
#pragma unroll
                for (int n = 0; n < 8; n++)
                    racc[m][n] = __builtin_amdgcn_mfma_f32_16x16x32_bf16(
                        A[m], B[n], racc[m][n], 0, 0, 0);
        }
        __syncthreads();
    }

    // ---- phase 3: epilogue, f32 res -> LDS, coalesced f32 [res|feat] store ----
    float* rlds = (float*)smem;   // qlds/wlds dead now (final barrier above)
#pragma unroll
    for (int m = 0; m < 4; m++)
#pragma unroll
        for (int n = 0; n < 8; n++)
#pragma unroll
            for (int r = 0; r < 4; r++)
                rlds[(wr * 64 + m * 16 + crow + r) * RS + wc * 128 + n * 16 + lrow] =
                    racc[m][n][r];
    __syncthreads();

#pragma unroll
    for (int base = 0; base < 128; base += 4) {
        int row = base + wid;
        f32x4_t a = *(const f32x4_t*)(rlds + row * RS + ln * 4);
        f32x4_t b = *(const f32x4_t*)(feat + (size_t)(r0 + row) * DMODEL + ln * 4);
        *(f32x4_t*)(out + (size_t)(r0 + row) * 512 + ln * 4)       = a;
        *(f32x4_t*)(out + (size_t)(r0 + row) * 512 + 256 + ln * 4) = b;
    }
}

// ---------------------------------------------------------------------------
extern "C" void kernel_launch(void* const* d_in, const int* in_sizes, int n_in,
                              void* d_out, int out_size, void* d_ws, size_t ws_size,
                              hipStream_t stream) {
    const float* p_xyz = (const float*)d_in[0];
    const float* feat  = (const float*)d_in[1];
    const float* Wq    = (const float*)d_in[2];
    const float* bq    = (const float*)d_in[3];
    const float* Wk    = (const float*)d_in[4];
    const float* bk    = (const float*)d_in[5];
    const float* Wv    = (const float*)d_in[6];
    const float* bv    = (const float*)d_in[7];
    float* out = (float*)d_out;

    char* ws = (char*)d_ws;
    unsigned long long* slots = (unsigned long long*)ws;                //  16 KB [2][NW][SLW]
    int*                idx   = (int*)(ws + 16384);                     //   4 KB
    unsigned short*     k_s   = (unsigned short*)(ws + 32768);          // 512 KB
    unsigned short*     vT    = (unsigned short*)(ws + 32768 + 524288); // 512 KB

    hipMemsetAsync(d_ws, 0, 16384, stream);   // invalidate slots every call

    hipLaunchKernelGGL(fps_kernel, dim3(NW), dim3(64), 0, stream,
                       p_xyz, slots, idx);
    hipLaunchKernelGGL(kv_kernel, dim3(MSAMP / 4), dim3(256), 0, stream,
                       feat, Wk, bk, Wv, bv, idx, k_s, vT);
    hipFuncSetAttribute((const void*)main_kernel,
                        hipFuncAttributeMaxDynamicSharedMemorySize, MAIN_LDS);
    hipLaunchKernelGGL(main_kernel, dim3(N_PTS / 128), dim3(256), MAIN_LDS, stream,
                       feat, Wq, bq, k_s, vT, out);
}